// Round 1
// baseline (5612.544 us; speedup 1.0000x reference)
//
#include <hip/hip_runtime.h>
#include <math.h>

#define D 128
#define T 2048
#define BATCH 4
#define HMID 512
#define NLAYER 12

// ---------------- embedding: H = tokemb(x) + pos ----------------
__global__ __launch_bounds__(256) void embed_kernel(const int* __restrict__ x,
                                                    const float* __restrict__ pos,
                                                    float* __restrict__ H) {
    int idx = blockIdx.x * 256 + threadIdx.x;   // [0, B*T*D)
    int d = idx & (D - 1);
    int bt = idx >> 7;
    float e = 0.f;
    if (d < 64) {
        float diff = (float)d - (float)x[bt];
        e = -0.5f * diff * diff;
    }
    H[idx] = e + pos[idx & (T * D - 1)];
}

// ---------------- layernorm: wave per token ----------------
__global__ __launch_bounds__(256) void ln_kernel(const float* __restrict__ Hin,
                                                 float* __restrict__ Hout,
                                                 const float* __restrict__ g,
                                                 const float* __restrict__ b) {
    int lane = threadIdx.x & 63;
    int tok = blockIdx.x * 4 + (threadIdx.x >> 6);
    const float* row = Hin + (size_t)tok * D;
    float h0 = row[lane], h1 = row[lane + 64];
    float s = h0 + h1;
#pragma unroll
    for (int off = 32; off; off >>= 1) s += __shfl_xor(s, off);
    float mu = s * (1.f / D);
    float d0 = h0 - mu, d1 = h1 - mu;
    float vs = d0 * d0 + d1 * d1;
#pragma unroll
    for (int off = 32; off; off >>= 1) vs += __shfl_xor(vs, off);
    float rstd = rsqrtf(vs * (1.f / D) + 1e-5f);
    float* orow = Hout + (size_t)tok * D;
    orow[lane] = d0 * rstd * g[lane] + b[lane];
    orow[lane + 64] = d1 * rstd * g[lane + 64] + b[lane + 64];
}

// ---------------- generic C = act(A @ W^T + bias) [+ resid] ----------------
// A: [M,K] row-major, W: [N,K] row-major (torch Linear layout), C: [M,N]
// Tiles 64x64x32, 256 threads, 4x4 microtile. ACT: 0=none, 1=exact gelu.
template <int ACT, int RESID>
__global__ __launch_bounds__(256) void gemm_nt(const float* __restrict__ A,
                                               const float* __restrict__ W,
                                               const float* __restrict__ bias,
                                               const float* __restrict__ Rin,
                                               float* __restrict__ C,
                                               int M, int N, int K) {
    __shared__ float As[32][68];   // As[k][m], pad 68 keeps float4 align + spreads banks
    __shared__ float Ws[32][68];   // Ws[k][n]
    const int tid = threadIdx.x;
    const int m0 = blockIdx.x * 64;
    const int n0 = blockIdx.y * 64;
    const int tm = (tid >> 4) * 4;
    const int tn = (tid & 15) * 4;
    const int lr = tid >> 3;         // 0..31
    const int lc = (tid & 7) * 4;    // 0..28
    float acc[4][4] = {};
    for (int k0 = 0; k0 < K; k0 += 32) {
        float4 a0 = *(const float4*)(A + (size_t)(m0 + lr) * K + k0 + lc);
        float4 a1 = *(const float4*)(A + (size_t)(m0 + lr + 32) * K + k0 + lc);
        float4 w0 = *(const float4*)(W + (size_t)(n0 + lr) * K + k0 + lc);
        float4 w1 = *(const float4*)(W + (size_t)(n0 + lr + 32) * K + k0 + lc);
        __syncthreads();
        As[lc + 0][lr] = a0.x; As[lc + 1][lr] = a0.y; As[lc + 2][lr] = a0.z; As[lc + 3][lr] = a0.w;
        As[lc + 0][lr + 32] = a1.x; As[lc + 1][lr + 32] = a1.y; As[lc + 2][lr + 32] = a1.z; As[lc + 3][lr + 32] = a1.w;
        Ws[lc + 0][lr] = w0.x; Ws[lc + 1][lr] = w0.y; Ws[lc + 2][lr] = w0.z; Ws[lc + 3][lr] = w0.w;
        Ws[lc + 0][lr + 32] = w1.x; Ws[lc + 1][lr + 32] = w1.y; Ws[lc + 2][lr + 32] = w1.z; Ws[lc + 3][lr + 32] = w1.w;
        __syncthreads();
#pragma unroll
        for (int kk = 0; kk < 32; kk++) {
            float4 av = *(const float4*)&As[kk][tm];
            float4 wv = *(const float4*)&Ws[kk][tn];
            const float* ap = &av.x;
            const float* wp = &wv.x;
#pragma unroll
            for (int i = 0; i < 4; i++)
#pragma unroll
                for (int j = 0; j < 4; j++)
                    acc[i][j] = fmaf(ap[i], wp[j], acc[i][j]);
        }
    }
#pragma unroll
    for (int i = 0; i < 4; i++) {
        float4 o;
        float* op = &o.x;
#pragma unroll
        for (int j = 0; j < 4; j++) {
            float val = acc[i][j];
            if (bias) val += bias[n0 + tn + j];
            if (ACT == 1) val = 0.5f * val * (1.f + erff(val * 0.7071067811865475f));
            op[j] = val;
        }
        size_t off = (size_t)(m0 + tm + i) * N + n0 + tn;
        if (RESID) {
            float4 rv = *(const float4*)(Rin + off);
            o.x += rv.x; o.y += rv.y; o.z += rv.z; o.w += rv.w;
        }
        *(float4*)(C + off) = o;
    }
}

// ---------------- flash attention (fp32), H += softmax(qK^T/sqrt(D)) V ----------------
// block: 32 queries of one batch, 256 threads; loop over 32-key tiles.
__global__ __launch_bounds__(256) void attn_kernel(const float* __restrict__ q,
                                                   const float* __restrict__ k,
                                                   const float* __restrict__ v,
                                                   float* __restrict__ H) {
    __shared__ float qs[32][132];
    __shared__ float Kt[32][132];
    __shared__ float Vt[32][132];
    __shared__ float Ss[32][33];
    __shared__ float alpha_s[32];
    __shared__ float l_s[32];
    const int tid = threadIdx.x;
    const int b = blockIdx.y;
    const int q0 = blockIdx.x * 32;
    const float* qb = q + ((size_t)b * T + q0) * D;
    const float* kb = k + (size_t)b * T * D;
    const float* vb = v + (size_t)b * T * D;

    // load q tile (32x128)
    for (int i = tid; i < 32 * 32; i += 256) {
        int r = i >> 5, c4 = (i & 31) << 2;
        *(float4*)&qs[r][c4] = *(const float4*)(qb + r * D + c4);
    }

    const int r2 = tid >> 4;        // S rows r2, r2+16
    const int c2 = tid & 15;        // S cols c2, c2+16
    const int orow = tid >> 3;      // O row (8 threads per row)
    const int od = (tid & 7) * 4;   // O d-base; elements od + 32*u + j (conflict-free)

    float O[16];
#pragma unroll
    for (int i = 0; i < 16; i++) O[i] = 0.f;
    float m_r = -1e30f, l_r = 0.f;
    const float rscale = 0.088388347648318447f;  // 1/sqrt(128)

    for (int kt = 0; kt < T / 32; kt++) {
        __syncthreads();  // protect Kt/Vt vs previous O-phase
        for (int i = tid; i < 32 * 32; i += 256) {
            int r = i >> 5, c4 = (i & 31) << 2;
            size_t goff = (size_t)(kt * 32 + r) * D + c4;
            *(float4*)&Kt[r][c4] = *(const float4*)(kb + goff);
            *(float4*)&Vt[r][c4] = *(const float4*)(vb + goff);
        }
        __syncthreads();
        // S = q K^T (2x2 per thread)
        float s00 = 0.f, s01 = 0.f, s10 = 0.f, s11 = 0.f;
#pragma unroll 8
        for (int kk = 0; kk < 32; kk++) {
            float4 aA = *(const float4*)&qs[r2][kk * 4];
            float4 aB = *(const float4*)&qs[r2 + 16][kk * 4];
            float4 bA = *(const float4*)&Kt[c2][kk * 4];
            float4 bB = *(const float4*)&Kt[c2 + 16][kk * 4];
            s00 += aA.x * bA.x + aA.y * bA.y + aA.z * bA.z + aA.w * bA.w;
            s01 += aA.x * bB.x + aA.y * bB.y + aA.z * bB.z + aA.w * bB.w;
            s10 += aB.x * bA.x + aB.y * bA.y + aB.z * bA.z + aB.w * bA.w;
            s11 += aB.x * bB.x + aB.y * bB.y + aB.z * bB.z + aB.w * bB.w;
        }
        Ss[r2][c2] = s00 * rscale;
        Ss[r2][c2 + 16] = s01 * rscale;
        Ss[r2 + 16][c2] = s10 * rscale;
        Ss[r2 + 16][c2 + 16] = s11 * rscale;
        __syncthreads();
        // online softmax, one thread per row
        if (tid < 32) {
            float mx = m_r;
#pragma unroll
            for (int c = 0; c < 32; c++) mx = fmaxf(mx, Ss[tid][c]);
            float alpha = expf(m_r - mx);
            float ps = 0.f;
#pragma unroll
            for (int c = 0; c < 32; c++) {
                float p = expf(Ss[tid][c] - mx);
                Ss[tid][c] = p;
                ps += p;
            }
            l_r = l_r * alpha + ps;
            m_r = mx;
            alpha_s[tid] = alpha;
            l_s[tid] = l_r;
        }
        __syncthreads();
        // O = O*alpha + P V
        float al = alpha_s[orow];
#pragma unroll
        for (int i = 0; i < 16; i++) O[i] *= al;
#pragma unroll 4
        for (int c = 0; c < 32; c++) {
            float p = Ss[orow][c];
#pragma unroll
            for (int u = 0; u < 4; u++) {
                float4 vv = *(const float4*)&Vt[c][od + 32 * u];
                O[u * 4 + 0] = fmaf(p, vv.x, O[u * 4 + 0]);
                O[u * 4 + 1] = fmaf(p, vv.y, O[u * 4 + 1]);
                O[u * 4 + 2] = fmaf(p, vv.z, O[u * 4 + 2]);
                O[u * 4 + 3] = fmaf(p, vv.w, O[u * 4 + 3]);
            }
        }
    }
    // epilogue: H += O / l
    float rl = 1.f / l_s[orow];
    float* Hrow = H + ((size_t)b * T + q0 + orow) * D;
#pragma unroll
    for (int u = 0; u < 4; u++) {
        float4 hv = *(const float4*)(Hrow + od + 32 * u);
        hv.x += O[u * 4 + 0] * rl;
        hv.y += O[u * 4 + 1] * rl;
        hv.z += O[u * 4 + 2] * rl;
        hv.w += O[u * 4 + 3] * rl;
        *(float4*)(Hrow + od + 32 * u) = hv;
    }
}

// ---------------- final projection: out[b,t] = H[b,t,:].Wro + bro ----------------
__global__ __launch_bounds__(256) void final_kernel(const float* __restrict__ H,
                                                    const float* __restrict__ Wro,
                                                    const float* __restrict__ bro,
                                                    float* __restrict__ out) {
    int lane = threadIdx.x & 63;
    int tok = blockIdx.x * 4 + (threadIdx.x >> 6);
    const float* row = H + (size_t)tok * D;
    float s = row[lane] * Wro[lane] + row[lane + 64] * Wro[lane + 64];
#pragma unroll
    for (int off = 32; off; off >>= 1) s += __shfl_xor(s, off);
    if (lane == 0) out[tok] = s + bro[0];
}

extern "C" void kernel_launch(void* const* d_in, const int* in_sizes, int n_in,
                              void* d_out, int out_size, void* d_ws, size_t ws_size,
                              hipStream_t stream) {
    const int* x = (const int*)d_in[0];
    const float* pos = (const float*)d_in[1];
    const float* Wq = (const float*)d_in[2];
    const float* Wk = (const float*)d_in[3];
    const float* Wv = (const float*)d_in[4];
    const float* ln1g = (const float*)d_in[5];
    const float* ln1b = (const float*)d_in[6];
    const float* W1 = (const float*)d_in[7];
    const float* b1 = (const float*)d_in[8];
    const float* W2 = (const float*)d_in[9];
    const float* b2 = (const float*)d_in[10];
    const float* ln2g = (const float*)d_in[11];
    const float* ln2b = (const float*)d_in[12];
    const float* Wro = (const float*)d_in[13];
    const float* bro = (const float*)d_in[14];
    float* out = (float*)d_out;

    const size_t NTOK = (size_t)BATCH * T;     // 8192
    const size_t HSZ = NTOK * D;               // 1,048,576 floats
    float* ws = (float*)d_ws;
    float* H   = ws;
    float* Hn  = ws + HSZ;
    float* qb  = ws + 2 * HSZ;
    float* kb  = ws + 3 * HSZ;
    float* vb  = ws + 4 * HSZ;
    float* mid = ws + 5 * HSZ;                 // 8192 x 512 -> total 36 MB of ws

    embed_kernel<<<dim3(HSZ / 256), 256, 0, stream>>>(x, pos, H);

    for (int l = 0; l < NLAYER; l++) {
        ln_kernel<<<dim3(NTOK / 4), 256, 0, stream>>>(H, Hn, ln1g + l * D, ln1b + l * D);
        gemm_nt<0, 0><<<dim3(128, 2), 256, 0, stream>>>(Hn, Wq + (size_t)l * D * D, nullptr, nullptr, qb, NTOK, D, D);
        gemm_nt<0, 0><<<dim3(128, 2), 256, 0, stream>>>(Hn, Wk + (size_t)l * D * D, nullptr, nullptr, kb, NTOK, D, D);
        gemm_nt<0, 0><<<dim3(128, 2), 256, 0, stream>>>(Hn, Wv + (size_t)l * D * D, nullptr, nullptr, vb, NTOK, D, D);
        attn_kernel<<<dim3(T / 32, BATCH), 256, 0, stream>>>(qb, kb, vb, H);
        ln_kernel<<<dim3(NTOK / 4), 256, 0, stream>>>(H, Hn, ln2g + l * D, ln2b + l * D);
        gemm_nt<1, 0><<<dim3(128, 8), 256, 0, stream>>>(Hn, W1 + (size_t)l * HMID * D, b1 + l * HMID, nullptr, mid, NTOK, HMID, D);
        gemm_nt<0, 1><<<dim3(128, 2), 256, 0, stream>>>(mid, W2 + (size_t)l * D * HMID, b2 + l * D, H, H, NTOK, D, HMID);
    }

    final_kernel<<<dim3(NTOK / 4), 256, 0, stream>>>(H, Wro, bro, out);
}

// Round 2
// 1413.506 us; speedup vs baseline: 3.9707x; 3.9707x over previous
//
#include <hip/hip_runtime.h>
#include <math.h>

#define D 128
#define T 2048
#define BATCH 4
#define HMID 512
#define NLAYER 12

#define KSPLIT 8
#define KPB (T / KSPLIT)   // 256 keys per block
#define BK 64
#define KS_P 136           // Ks pitch (shorts): 128 + 8 pad, keeps 16B align
#define VT_P 72            // Vt pitch: 64 + 8
#define PS_P 72            // Ps pitch: 64 + 8

typedef unsigned short u16;
typedef __attribute__((ext_vector_type(8))) short bf16x8;
typedef __attribute__((ext_vector_type(16))) float f32x16;

__device__ inline u16 f2bf(float x) {
    unsigned u = __builtin_bit_cast(unsigned, x);
    return (u16)((u + 0x7FFFu + ((u >> 16) & 1u)) >> 16);
}
__device__ inline float bf2f(u16 v) {
    return __builtin_bit_cast(float, (unsigned)v << 16);
}

// ---------------- embedding: H = tokemb(x) + pos ----------------
__global__ __launch_bounds__(256) void embed_kernel(const int* __restrict__ x,
                                                    const float* __restrict__ pos,
                                                    float* __restrict__ H) {
    int idx = blockIdx.x * 256 + threadIdx.x;
    int d = idx & (D - 1);
    int bt = idx >> 7;
    float e = 0.f;
    if (d < 64) {
        float diff = (float)d - (float)x[bt];
        e = -0.5f * diff * diff;
    }
    H[idx] = e + pos[idx & (T * D - 1)];
}

// ---------------- layernorm: wave per token ----------------
__global__ __launch_bounds__(256) void ln_kernel(const float* __restrict__ Hin,
                                                 float* __restrict__ Hout,
                                                 const float* __restrict__ g,
                                                 const float* __restrict__ b) {
    int lane = threadIdx.x & 63;
    int tok = blockIdx.x * 4 + (threadIdx.x >> 6);
    const float* row = Hin + (size_t)tok * D;
    float h0 = row[lane], h1 = row[lane + 64];
    float s = h0 + h1;
#pragma unroll
    for (int off = 32; off; off >>= 1) s += __shfl_xor(s, off);
    float mu = s * (1.f / D);
    float d0 = h0 - mu, d1 = h1 - mu;
    float vs = d0 * d0 + d1 * d1;
#pragma unroll
    for (int off = 32; off; off >>= 1) vs += __shfl_xor(vs, off);
    float rstd = rsqrtf(vs * (1.f / D) + 1e-5f);
    float* orow = Hout + (size_t)tok * D;
    orow[lane] = d0 * rstd * g[lane] + b[lane];
    orow[lane + 64] = d1 * rstd * g[lane + 64] + b[lane + 64];
}

// ---------------- generic C = act(A @ W^T + bias) [+resid] ----------------
// OUT: 0 = f32 row-major, 1 = bf16 row-major (scaled), 2 = bf16 transposed per batch
template <int ACT, int RESID, int OUT>
__global__ __launch_bounds__(256) void gemm_nt(const float* __restrict__ A,
                                               const float* __restrict__ W,
                                               const float* __restrict__ bias,
                                               const float* __restrict__ Rin,
                                               void* __restrict__ Cout,
                                               int M, int N, int K, float scale) {
    __shared__ float As[32][68];
    __shared__ float Ws[32][68];
    const int tid = threadIdx.x;
    const int m0 = blockIdx.x * 64;
    const int n0 = blockIdx.y * 64;
    const int tm = (tid >> 4) * 4;
    const int tn = (tid & 15) * 4;
    const int lr = tid >> 3;
    const int lc = (tid & 7) * 4;
    float acc[4][4] = {};
    for (int k0 = 0; k0 < K; k0 += 32) {
        float4 a0 = *(const float4*)(A + (size_t)(m0 + lr) * K + k0 + lc);
        float4 a1 = *(const float4*)(A + (size_t)(m0 + lr + 32) * K + k0 + lc);
        float4 w0 = *(const float4*)(W + (size_t)(n0 + lr) * K + k0 + lc);
        float4 w1 = *(const float4*)(W + (size_t)(n0 + lr + 32) * K + k0 + lc);
        __syncthreads();
        As[lc + 0][lr] = a0.x; As[lc + 1][lr] = a0.y; As[lc + 2][lr] = a0.z; As[lc + 3][lr] = a0.w;
        As[lc + 0][lr + 32] = a1.x; As[lc + 1][lr + 32] = a1.y; As[lc + 2][lr + 32] = a1.z; As[lc + 3][lr + 32] = a1.w;
        Ws[lc + 0][lr] = w0.x; Ws[lc + 1][lr] = w0.y; Ws[lc + 2][lr] = w0.z; Ws[lc + 3][lr] = w0.w;
        Ws[lc + 0][lr + 32] = w1.x; Ws[lc + 1][lr + 32] = w1.y; Ws[lc + 2][lr + 32] = w1.z; Ws[lc + 3][lr + 32] = w1.w;
        __syncthreads();
#pragma unroll
        for (int kk = 0; kk < 32; kk++) {
            float4 av = *(const float4*)&As[kk][tm];
            float4 wv = *(const float4*)&Ws[kk][tn];
            const float* ap = &av.x;
            const float* wp = &wv.x;
#pragma unroll
            for (int i = 0; i < 4; i++)
#pragma unroll
                for (int j = 0; j < 4; j++)
                    acc[i][j] = fmaf(ap[i], wp[j], acc[i][j]);
        }
    }
#pragma unroll
    for (int i = 0; i < 4; i++)
#pragma unroll
        for (int j = 0; j < 4; j++) {
            float val = acc[i][j];
            if (bias) val += bias[n0 + tn + j];
            if (ACT == 1) val = 0.5f * val * (1.f + erff(val * 0.7071067811865475f));
            acc[i][j] = val;
        }
    if (OUT == 0) {
        float* C = (float*)Cout;
#pragma unroll
        for (int i = 0; i < 4; i++) {
            float4 o = {acc[i][0], acc[i][1], acc[i][2], acc[i][3]};
            size_t off = (size_t)(m0 + tm + i) * N + n0 + tn;
            if (RESID) {
                float4 rv = *(const float4*)(Rin + off);
                o.x += rv.x; o.y += rv.y; o.z += rv.z; o.w += rv.w;
            }
            *(float4*)(C + off) = o;
        }
    } else if (OUT == 1) {
        u16* C = (u16*)Cout;
#pragma unroll
        for (int i = 0; i < 4; i++) {
            ushort4 o;
            o.x = f2bf(acc[i][0] * scale);
            o.y = f2bf(acc[i][1] * scale);
            o.z = f2bf(acc[i][2] * scale);
            o.w = f2bf(acc[i][3] * scale);
            *(ushort4*)(C + (size_t)(m0 + tm + i) * N + n0 + tn) = o;
        }
    } else {  // OUT == 2: C^T per batch, [b][n][m-local], pitch T
        int bb = m0 >> 11;  // m0 / T
        u16* C = (u16*)Cout + (size_t)bb * D * T;
        int mloc = m0 - bb * T + tm;
#pragma unroll
        for (int j = 0; j < 4; j++) {
            ushort4 o;
            o.x = f2bf(acc[0][j]);
            o.y = f2bf(acc[1][j]);
            o.z = f2bf(acc[2][j]);
            o.w = f2bf(acc[3][j]);
            *(ushort4*)(C + (size_t)(n0 + tn + j) * T + mloc) = o;
        }
    }
}

// ---------------- MFMA flash attention (bf16), split-K partials ----------------
// Q pre-scaled by log2(e)/sqrt(D); softmax in exp2 domain.
// block: 4 waves x 32 q-rows = 128 q, KPB keys; grid (64 qblk, KSPLIT)
__global__ __launch_bounds__(256, 2) void attn_mfma(const u16* __restrict__ qg,
                                                    const u16* __restrict__ kg,
                                                    const u16* __restrict__ vtg,
                                                    u16* __restrict__ Op,
                                                    float* __restrict__ ml) {
    __shared__ u16 Ks[64 * KS_P];        // [key][d]
    __shared__ u16 Vt[D * VT_P];         // [d][key]
    __shared__ u16 Ps[4][32 * PS_P];     // per wave: [q][key]

    const int tid = threadIdx.x;
    const int w = tid >> 6;
    const int l = tid & 63;
    const int h = l >> 5;
    const int ql = l & 31;
    const int qblk = blockIdx.x;
    const int ks = blockIdx.y;
    const int b = qblk >> 4;

    // Q fragments (B operand of S^T): lane q = qblk*128 + w*32 + ql
    const size_t qrow = (size_t)qblk * 128 + w * 32 + ql;
    bf16x8 qf[8];
#pragma unroll
    for (int c = 0; c < 8; c++)
        qf[c] = *(const bf16x8*)(qg + qrow * D + c * 16 + h * 8);

    f32x16 ot[4];
#pragma unroll
    for (int t = 0; t < 4; t++)
#pragma unroll
        for (int r = 0; r < 16; r++) ot[t][r] = 0.f;
    float m_run = -1e30f, l_run = 0.f;

    const size_t kgb = (size_t)b * T * D;
    const size_t vtb = (size_t)b * D * T;

    for (int kt = 0; kt < KPB / BK; kt++) {
        const int kbase = ks * KPB + kt * BK;
        __syncthreads();
        // stage K tile [64][128]
#pragma unroll
        for (int i = 0; i < 4; i++) {
            int ci = tid + 256 * i;
            int row = ci >> 4, cc = ci & 15;
            *(uint4*)&Ks[row * KS_P + cc * 8] =
                *(const uint4*)(kg + kgb + (size_t)(kbase + row) * D + cc * 8);
        }
        // stage V^T tile [128][64]
#pragma unroll
        for (int i = 0; i < 4; i++) {
            int ci = tid + 256 * i;
            int dd = ci >> 3, kc = ci & 7;
            *(uint4*)&Vt[dd * VT_P + kc * 8] =
                *(const uint4*)(vtg + vtb + (size_t)dd * T + kbase + kc * 8);
        }
        __syncthreads();
        // S^T = K * Q^T  (2 key tiles of 32)
        f32x16 st0, st1;
#pragma unroll
        for (int r = 0; r < 16; r++) { st0[r] = 0.f; st1[r] = 0.f; }
#pragma unroll
        for (int c = 0; c < 8; c++) {
            bf16x8 k0 = *(const bf16x8*)&Ks[(ql) * KS_P + c * 16 + h * 8];
            bf16x8 k1 = *(const bf16x8*)&Ks[(32 + ql) * KS_P + c * 16 + h * 8];
            st0 = __builtin_amdgcn_mfma_f32_32x32x16_bf16(k0, qf[c], st0, 0, 0, 0);
            st1 = __builtin_amdgcn_mfma_f32_32x32x16_bf16(k1, qf[c], st1, 0, 0, 0);
        }
        // online softmax: per-lane stats (lane's q = col), exp2 domain
        float mx = m_run;
#pragma unroll
        for (int r = 0; r < 16; r++) mx = fmaxf(mx, fmaxf(st0[r], st1[r]));
        mx = fmaxf(mx, __shfl_xor(mx, 32));
        float alpha = exp2f(m_run - mx);
        m_run = mx;
        float rs = 0.f;
#pragma unroll
        for (int r = 0; r < 16; r++) {
            float p0 = exp2f(st0[r] - mx); st0[r] = p0;
            float p1 = exp2f(st1[r] - mx); st1[r] = p1;
            rs += p0 + p1;
        }
        rs += __shfl_xor(rs, 32);
        l_run = l_run * alpha + rs;
        // write P (row-major [q][key]) — C-layout regs 4g..4g+3 are 4 contiguous keys
        u16* pw = &Ps[w][ql * PS_P];
#pragma unroll
        for (int g = 0; g < 4; g++) {
            ushort4 p0, p1;
            p0.x = f2bf(st0[4 * g + 0]); p0.y = f2bf(st0[4 * g + 1]);
            p0.z = f2bf(st0[4 * g + 2]); p0.w = f2bf(st0[4 * g + 3]);
            p1.x = f2bf(st1[4 * g + 0]); p1.y = f2bf(st1[4 * g + 1]);
            p1.z = f2bf(st1[4 * g + 2]); p1.w = f2bf(st1[4 * g + 3]);
            *(ushort4*)(pw + g * 8 + h * 4) = p0;
            *(ushort4*)(pw + 32 + g * 8 + h * 4) = p1;
        }
        // O^T = O^T*alpha + V^T * P^T
#pragma unroll
        for (int t = 0; t < 4; t++)
#pragma unroll
            for (int r = 0; r < 16; r++) ot[t][r] *= alpha;
#pragma unroll
        for (int c = 0; c < 4; c++) {
            bf16x8 pf = *(const bf16x8*)&Ps[w][ql * PS_P + c * 16 + h * 8];
#pragma unroll
            for (int t = 0; t < 4; t++) {
                bf16x8 vf = *(const bf16x8*)&Vt[(t * 32 + ql) * VT_P + c * 16 + h * 8];
                ot[t] = __builtin_amdgcn_mfma_f32_32x32x16_bf16(vf, pf, ot[t], 0, 0, 0);
            }
        }
    }
    // write partials: Op layout [qblk][ks][w][d 128][q 32] bf16 (coalesced along q)
    size_t base = (((size_t)(qblk * KSPLIT + ks)) * 4 + w) * (128 * 32);
#pragma unroll
    for (int t = 0; t < 4; t++)
#pragma unroll
        for (int r = 0; r < 16; r++) {
            int dd = (r & 3) + 8 * (r >> 2) + 4 * h + 32 * t;
            Op[base + (size_t)dd * 32 + ql] = f2bf(ot[t][r]);
        }
    if (h == 0) {
        int qi = w * 32 + ql;
        ml[(size_t)(qblk * KSPLIT + ks) * 256 + qi] = m_run;
        ml[(size_t)(qblk * KSPLIT + ks) * 256 + 128 + qi] = l_run;
    }
}

// ---------------- merge split-K partials, H += attn out ----------------
__global__ __launch_bounds__(256) void attn_merge(const u16* __restrict__ Op,
                                                  const float* __restrict__ ml,
                                                  float* __restrict__ H) {
    __shared__ float Os[128][33];
    const int qblk = blockIdx.x;
    const int ds0 = blockIdx.y * 32;
    const int tid = threadIdx.x;
    const int ql = tid & 31;
    const int w = (tid >> 5) & 3;
    const int half = tid >> 7;
    const int qin = w * 32 + ql;
    float m[KSPLIT], lv[KSPLIT];
    float M = -1e30f;
#pragma unroll
    for (int ks = 0; ks < KSPLIT; ks++) {
        m[ks] = ml[(size_t)(qblk * KSPLIT + ks) * 256 + qin];
        lv[ks] = ml[(size_t)(qblk * KSPLIT + ks) * 256 + 128 + qin];
        M = fmaxf(M, m[ks]);
    }
    float L = 0.f, f[KSPLIT];
#pragma unroll
    for (int ks = 0; ks < KSPLIT; ks++) { f[ks] = exp2f(m[ks] - M); L += lv[ks] * f[ks]; }
    float invL = 1.f / L;
#pragma unroll
    for (int i = 0; i < 16; i++) {
        int d = ds0 + half * 16 + i;
        float acc = 0.f;
#pragma unroll
        for (int ks = 0; ks < KSPLIT; ks++) {
            u16 u = Op[((((size_t)(qblk * KSPLIT + ks)) * 4 + w) * 128 + d) * 32 + ql];
            acc += bf2f(u) * f[ks];
        }
        Os[qin][half * 16 + i] = acc * invL;
    }
    __syncthreads();
    const size_t row0 = (size_t)qblk * 128;
#pragma unroll
    for (int j = 0; j < 16; j++) {
        int idx = tid + 256 * j;
        int q2 = idx >> 5;
        int dl = idx & 31;
        H[(row0 + q2) * D + ds0 + dl] += Os[q2][dl];
    }
}

// ---------------- final projection ----------------
__global__ __launch_bounds__(256) void final_kernel(const float* __restrict__ H,
                                                    const float* __restrict__ Wro,
                                                    const float* __restrict__ bro,
                                                    float* __restrict__ out) {
    int lane = threadIdx.x & 63;
    int tok = blockIdx.x * 4 + (threadIdx.x >> 6);
    const float* row = H + (size_t)tok * D;
    float s = row[lane] * Wro[lane] + row[lane + 64] * Wro[lane + 64];
#pragma unroll
    for (int off = 32; off; off >>= 1) s += __shfl_xor(s, off);
    if (lane == 0) out[tok] = s + bro[0];
}

extern "C" void kernel_launch(void* const* d_in, const int* in_sizes, int n_in,
                              void* d_out, int out_size, void* d_ws, size_t ws_size,
                              hipStream_t stream) {
    const int* x = (const int*)d_in[0];
    const float* pos = (const float*)d_in[1];
    const float* Wq = (const float*)d_in[2];
    const float* Wk = (const float*)d_in[3];
    const float* Wv = (const float*)d_in[4];
    const float* ln1g = (const float*)d_in[5];
    const float* ln1b = (const float*)d_in[6];
    const float* W1 = (const float*)d_in[7];
    const float* b1 = (const float*)d_in[8];
    const float* W2 = (const float*)d_in[9];
    const float* b2 = (const float*)d_in[10];
    const float* ln2g = (const float*)d_in[11];
    const float* ln2b = (const float*)d_in[12];
    const float* Wro = (const float*)d_in[13];
    const float* bro = (const float*)d_in[14];
    float* out = (float*)d_out;

    const size_t NTOK = (size_t)BATCH * T;  // 8192
    const size_t HSZ = NTOK * D;            // 1,048,576
    float* ws = (float*)d_ws;
    float* H = ws;                          // f32 [8192][128]
    float* Hn = ws + HSZ;                   // f32 [8192][128]
    u16* qb = (u16*)(ws + 2 * HSZ);         // bf16 [8192][128]
    u16* kb = (u16*)(ws + 2 * HSZ + HSZ / 2);
    u16* vt = (u16*)(ws + 3 * HSZ);         // bf16 [B][128][2048]
    float* mlbuf = ws + 3 * HSZ + HSZ / 2;  // f32 64*8*2*128 = 131072
    float* mid = ws + 3 * HSZ + HSZ / 2 + 131072;  // f32 [8192][512]
    u16* Op = (u16*)mid;                    // bf16 partials (aliases mid; disjoint lifetime)

    const float qscale = 1.4426950408889634f / 11.313708498984761f;  // log2(e)/sqrt(D)

    embed_kernel<<<dim3(HSZ / 256), 256, 0, stream>>>(x, pos, H);

    for (int l = 0; l < NLAYER; l++) {
        ln_kernel<<<dim3(NTOK / 4), 256, 0, stream>>>(H, Hn, ln1g + l * D, ln1b + l * D);
        gemm_nt<0, 0, 1><<<dim3(128, 2), 256, 0, stream>>>(Hn, Wq + (size_t)l * D * D, nullptr, nullptr, qb, NTOK, D, D, qscale);
        gemm_nt<0, 0, 1><<<dim3(128, 2), 256, 0, stream>>>(Hn, Wk + (size_t)l * D * D, nullptr, nullptr, kb, NTOK, D, D, 1.f);
        gemm_nt<0, 0, 2><<<dim3(128, 2), 256, 0, stream>>>(Hn, Wv + (size_t)l * D * D, nullptr, nullptr, vt, NTOK, D, D, 1.f);
        attn_mfma<<<dim3(64, KSPLIT), 256, 0, stream>>>(qb, kb, vt, Op, mlbuf);
        attn_merge<<<dim3(64, 4), 256, 0, stream>>>(Op, mlbuf, H);
        ln_kernel<<<dim3(NTOK / 4), 256, 0, stream>>>(H, Hn, ln2g + l * D, ln2b + l * D);
        gemm_nt<1, 0, 0><<<dim3(128, 8), 256, 0, stream>>>(Hn, W1 + (size_t)l * HMID * D, b1 + l * HMID, nullptr, mid, NTOK, HMID, D, 1.f);
        gemm_nt<0, 1, 0><<<dim3(128, 2), 256, 0, stream>>>(mid, W2 + (size_t)l * D * HMID, b2 + l * D, H, H, NTOK, D, HMID, 1.f);
    }

    final_kernel<<<dim3(NTOK / 4), 256, 0, stream>>>(H, Wro, bro, out);
}

// Round 3
// 1107.178 us; speedup vs baseline: 5.0692x; 1.2767x over previous
//
#include <hip/hip_runtime.h>
#include <math.h>

#define D 128
#define T 2048
#define BATCH 4
#define HMID 512
#define NLAYER 12

#define KSPLIT 8
#define KPB (T / KSPLIT)   // 256 keys per block
#define BK 64
#define KS_P 136           // Ks pitch (shorts)
#define VT_P 72
#define PS_P 72

typedef unsigned short u16;
typedef __attribute__((ext_vector_type(8))) short bf16x8;
typedef __attribute__((ext_vector_type(16))) float f32x16;

__device__ inline u16 f2bf(float x) {
    unsigned u = __builtin_bit_cast(unsigned, x);
    return (u16)((u + 0x7FFFu + ((u >> 16) & 1u)) >> 16);
}
__device__ inline float bf2f(u16 v) {
    return __builtin_bit_cast(float, (unsigned)v << 16);
}

// ---------------- embedding ----------------
__global__ __launch_bounds__(256) void embed_kernel(const int* __restrict__ x,
                                                    const float* __restrict__ pos,
                                                    float* __restrict__ H) {
    int idx = blockIdx.x * 256 + threadIdx.x;
    int d = idx & (D - 1);
    int bt = idx >> 7;
    float e = 0.f;
    if (d < 64) {
        float diff = (float)d - (float)x[bt];
        e = -0.5f * diff * diff;
    }
    H[idx] = e + pos[idx & (T * D - 1)];
}

// ---------------- layernorm -> bf16 ----------------
__global__ __launch_bounds__(256) void ln_kernel(const float* __restrict__ Hin,
                                                 u16* __restrict__ Hout,
                                                 const float* __restrict__ g,
                                                 const float* __restrict__ b) {
    int lane = threadIdx.x & 63;
    int tok = blockIdx.x * 4 + (threadIdx.x >> 6);
    const float* row = Hin + (size_t)tok * D;
    float h0 = row[lane], h1 = row[lane + 64];
    float s = h0 + h1;
#pragma unroll
    for (int off = 32; off; off >>= 1) s += __shfl_xor(s, off);
    float mu = s * (1.f / D);
    float d0 = h0 - mu, d1 = h1 - mu;
    float vs = d0 * d0 + d1 * d1;
#pragma unroll
    for (int off = 32; off; off >>= 1) vs += __shfl_xor(vs, off);
    float rstd = rsqrtf(vs * (1.f / D) + 1e-5f);
    u16* orow = Hout + (size_t)tok * D;
    orow[lane] = f2bf(d0 * rstd * g[lane] + b[lane]);
    orow[lane + 64] = f2bf(d1 * rstd * g[lane + 64] + b[lane + 64]);
}

// ---------------- weight conversion ----------------
__global__ __launch_bounds__(256) void conv_qkv(const float* __restrict__ Wq,
                                                const float* __restrict__ Wk,
                                                const float* __restrict__ Wv,
                                                u16* __restrict__ dst, float qscale) {
    int idx = blockIdx.x * 256 + threadIdx.x;  // L*3*128*128
    int l = idx / 49152;
    int rem = idx - l * 49152;
    int s = rem >> 14;
    int off = rem & 16383;
    const float* src = (s == 0) ? Wq : ((s == 1) ? Wk : Wv);
    float v = src[l * 16384 + off] * ((s == 0) ? qscale : 1.f);
    dst[idx] = f2bf(v);
}

__global__ __launch_bounds__(256) void conv_plain(const float* __restrict__ src,
                                                  u16* __restrict__ dst, int n) {
    int idx = blockIdx.x * 256 + threadIdx.x;
    if (idx < n) dst[idx] = f2bf(src[idx]);
}

// ---------------- MFMA GEMM: C = act(A @ W^T + bias) [+resid] ----------------
// A: [M][K] bf16 row-major; W: [N][K] bf16 row-major.
// Block tile 128 x BN, BK=64, 4 waves (2x2). OUT: 0=f32 (+resid), 1=bf16, 2=QKV split.
template <int ACT, int RESID, int OUT, int BN>
__global__ __launch_bounds__(256, 2) void gemm_bf16(const u16* __restrict__ A,
                                                    const u16* __restrict__ W,
                                                    const float* __restrict__ bias,
                                                    const float* __restrict__ Rin,
                                                    void* __restrict__ C0,
                                                    u16* __restrict__ Ckb,
                                                    u16* __restrict__ Cvt,
                                                    int M, int N, int K) {
    constexpr int WN = BN / 2;
    constexpr int NJ = WN / 32;
    __shared__ u16 As[8 * 128 * 8];
    __shared__ u16 Bs[8 * BN * 8];
    const int tid = threadIdx.x;
    const int w = tid >> 6;
    const int l = tid & 63;
    const int h = l >> 5;
    const int ql = l & 31;
    const int wm = w >> 1;
    const int wn = w & 1;
    const int m0 = blockIdx.x * 128;
    const int n0 = blockIdx.y * BN;
    const int ra = tid >> 3;     // 0..31
    const int cl = tid & 7;      // chunk for staging

    f32x16 acc[2][NJ];
#pragma unroll
    for (int i = 0; i < 2; i++)
#pragma unroll
        for (int j = 0; j < NJ; j++)
#pragma unroll
            for (int r = 0; r < 16; r++) acc[i][j][r] = 0.f;

    for (int kb = 0; kb < K; kb += 64) {
        __syncthreads();
#pragma unroll
        for (int i = 0; i < 4; i++) {
            uint4 av = *(const uint4*)(A + (size_t)(m0 + ra + 32 * i) * K + kb + cl * 8);
            *(uint4*)&As[(cl * 128 + ((ra + 32 * i) ^ cl)) * 8] = av;
        }
#pragma unroll
        for (int i = 0; i < BN / 32; i++) {
            uint4 bv = *(const uint4*)(W + (size_t)(n0 + ra + 32 * i) * K + kb + cl * 8);
            *(uint4*)&Bs[(cl * BN + ((ra + 32 * i) ^ cl)) * 8] = bv;
        }
        __syncthreads();
#pragma unroll
        for (int s = 0; s < 4; s++) {
            int ch = s * 2 + h;
            bf16x8 af[2], bfr[NJ];
#pragma unroll
            for (int i = 0; i < 2; i++)
                af[i] = *(const bf16x8*)&As[(ch * 128 + ((wm * 64 + i * 32 + ql) ^ ch)) * 8];
#pragma unroll
            for (int j = 0; j < NJ; j++)
                bfr[j] = *(const bf16x8*)&Bs[(ch * BN + ((wn * WN + j * 32 + ql) ^ ch)) * 8];
#pragma unroll
            for (int i = 0; i < 2; i++)
#pragma unroll
                for (int j = 0; j < NJ; j++)
                    acc[i][j] = __builtin_amdgcn_mfma_f32_32x32x16_bf16(af[i], bfr[j], acc[i][j], 0, 0, 0);
        }
    }

#pragma unroll
    for (int i = 0; i < 2; i++)
#pragma unroll
        for (int j = 0; j < NJ; j++) {
            const int nc = n0 + wn * WN + j * 32 + ql;
            float bv = bias ? bias[nc] : 0.f;
#pragma unroll
            for (int r = 0; r < 16; r++) {
                int mr = m0 + wm * 64 + i * 32 + 4 * h + 8 * (r >> 2) + (r & 3);
                float v = acc[i][j][r] + bv;
                if (ACT == 1) v = 0.5f * v * (1.f + erff(v * 0.7071067811865475f));
                if (OUT == 0) {
                    size_t off = (size_t)mr * N + nc;
                    if (RESID) v += Rin[off];
                    ((float*)C0)[off] = v;
                } else if (OUT == 1) {
                    ((u16*)C0)[(size_t)mr * N + nc] = f2bf(v);
                } else {
                    int slice = n0 >> 7;
                    int nl = nc & 127;
                    if (slice == 0) ((u16*)C0)[(size_t)mr * 128 + nl] = f2bf(v);
                    else if (slice == 1) Ckb[(size_t)mr * 128 + nl] = f2bf(v);
                    else {
                        int bb = mr >> 11, tl = mr & 2047;
                        Cvt[(size_t)bb * D * T + (size_t)nl * T + tl] = f2bf(v);
                    }
                }
            }
        }
}

// ---------------- MFMA flash attention (bf16), split-K partials ----------------
__global__ __launch_bounds__(256, 2) void attn_mfma(const u16* __restrict__ qg,
                                                    const u16* __restrict__ kg,
                                                    const u16* __restrict__ vtg,
                                                    u16* __restrict__ Op,
                                                    float* __restrict__ ml) {
    __shared__ u16 Ks[64 * KS_P];
    __shared__ u16 Vt[D * VT_P];
    __shared__ u16 Ps[4][32 * PS_P];

    const int tid = threadIdx.x;
    const int w = tid >> 6;
    const int l = tid & 63;
    const int h = l >> 5;
    const int ql = l & 31;
    const int qblk = blockIdx.x;
    const int ks = blockIdx.y;
    const int b = qblk >> 4;

    const size_t qrow = (size_t)qblk * 128 + w * 32 + ql;
    bf16x8 qf[8];
#pragma unroll
    for (int c = 0; c < 8; c++)
        qf[c] = *(const bf16x8*)(qg + qrow * D + c * 16 + h * 8);

    f32x16 ot[4];
#pragma unroll
    for (int t = 0; t < 4; t++)
#pragma unroll
        for (int r = 0; r < 16; r++) ot[t][r] = 0.f;
    float m_run = -1e30f, l_run = 0.f;

    const size_t kgb = (size_t)b * T * D;
    const size_t vtb = (size_t)b * D * T;

    for (int kt = 0; kt < KPB / BK; kt++) {
        const int kbase = ks * KPB + kt * BK;
        __syncthreads();
#pragma unroll
        for (int i = 0; i < 4; i++) {
            int ci = tid + 256 * i;
            int row = ci >> 4, cc = ci & 15;
            *(uint4*)&Ks[row * KS_P + cc * 8] =
                *(const uint4*)(kg + kgb + (size_t)(kbase + row) * D + cc * 8);
        }
#pragma unroll
        for (int i = 0; i < 4; i++) {
            int ci = tid + 256 * i;
            int dd = ci >> 3, kc = ci & 7;
            *(uint4*)&Vt[dd * VT_P + kc * 8] =
                *(const uint4*)(vtg + vtb + (size_t)dd * T + kbase + kc * 8);
        }
        __syncthreads();
        f32x16 st0, st1;
#pragma unroll
        for (int r = 0; r < 16; r++) { st0[r] = 0.f; st1[r] = 0.f; }
#pragma unroll
        for (int c = 0; c < 8; c++) {
            bf16x8 k0 = *(const bf16x8*)&Ks[(ql)*KS_P + c * 16 + h * 8];
            bf16x8 k1 = *(const bf16x8*)&Ks[(32 + ql) * KS_P + c * 16 + h * 8];
            st0 = __builtin_amdgcn_mfma_f32_32x32x16_bf16(k0, qf[c], st0, 0, 0, 0);
            st1 = __builtin_amdgcn_mfma_f32_32x32x16_bf16(k1, qf[c], st1, 0, 0, 0);
        }
        float mx = m_run;
#pragma unroll
        for (int r = 0; r < 16; r++) mx = fmaxf(mx, fmaxf(st0[r], st1[r]));
        mx = fmaxf(mx, __shfl_xor(mx, 32));
        float alpha = exp2f(m_run - mx);
        m_run = mx;
        float rs = 0.f;
#pragma unroll
        for (int r = 0; r < 16; r++) {
            float p0 = exp2f(st0[r] - mx); st0[r] = p0;
            float p1 = exp2f(st1[r] - mx); st1[r] = p1;
            rs += p0 + p1;
        }
        rs += __shfl_xor(rs, 32);
        l_run = l_run * alpha + rs;
        u16* pw = &Ps[w][ql * PS_P];
#pragma unroll
        for (int g = 0; g < 4; g++) {
            ushort4 p0, p1;
            p0.x = f2bf(st0[4 * g + 0]); p0.y = f2bf(st0[4 * g + 1]);
            p0.z = f2bf(st0[4 * g + 2]); p0.w = f2bf(st0[4 * g + 3]);
            p1.x = f2bf(st1[4 * g + 0]); p1.y = f2bf(st1[4 * g + 1]);
            p1.z = f2bf(st1[4 * g + 2]); p1.w = f2bf(st1[4 * g + 3]);
            *(ushort4*)(pw + g * 8 + h * 4) = p0;
            *(ushort4*)(pw + 32 + g * 8 + h * 4) = p1;
        }
#pragma unroll
        for (int t = 0; t < 4; t++)
#pragma unroll
            for (int r = 0; r < 16; r++) ot[t][r] *= alpha;
#pragma unroll
        for (int c = 0; c < 4; c++) {
            bf16x8 pf = *(const bf16x8*)&Ps[w][ql * PS_P + c * 16 + h * 8];
#pragma unroll
            for (int t = 0; t < 4; t++) {
                bf16x8 vf = *(const bf16x8*)&Vt[(t * 32 + ql) * VT_P + c * 16 + h * 8];
                ot[t] = __builtin_amdgcn_mfma_f32_32x32x16_bf16(vf, pf, ot[t], 0, 0, 0);
            }
        }
    }
    size_t base = (((size_t)(qblk * KSPLIT + ks)) * 4 + w) * (128 * 32);
#pragma unroll
    for (int t = 0; t < 4; t++)
#pragma unroll
        for (int r = 0; r < 16; r++) {
            int dd = (r & 3) + 8 * (r >> 2) + 4 * h + 32 * t;
            Op[base + (size_t)dd * 32 + ql] = f2bf(ot[t][r]);
        }
    if (h == 0) {
        int qi = w * 32 + ql;
        ml[(size_t)(qblk * KSPLIT + ks) * 256 + qi] = m_run;
        ml[(size_t)(qblk * KSPLIT + ks) * 256 + 128 + qi] = l_run;
    }
}

// ---------------- merge split-K partials, H += attn out ----------------
__global__ __launch_bounds__(256) void attn_merge(const u16* __restrict__ Op,
                                                  const float* __restrict__ ml,
                                                  float* __restrict__ H) {
    __shared__ float Os[128][33];
    const int qblk = blockIdx.x;
    const int ds0 = blockIdx.y * 32;
    const int tid = threadIdx.x;
    const int ql = tid & 31;
    const int w = (tid >> 5) & 3;
    const int half = tid >> 7;
    const int qin = w * 32 + ql;
    float m[KSPLIT], lv[KSPLIT];
    float M = -1e30f;
#pragma unroll
    for (int ks = 0; ks < KSPLIT; ks++) {
        m[ks] = ml[(size_t)(qblk * KSPLIT + ks) * 256 + qin];
        lv[ks] = ml[(size_t)(qblk * KSPLIT + ks) * 256 + 128 + qin];
        M = fmaxf(M, m[ks]);
    }
    float L = 0.f, f[KSPLIT];
#pragma unroll
    for (int ks = 0; ks < KSPLIT; ks++) { f[ks] = exp2f(m[ks] - M); L += lv[ks] * f[ks]; }
    float invL = 1.f / L;
#pragma unroll
    for (int i = 0; i < 16; i++) {
        int d = ds0 + half * 16 + i;
        float acc = 0.f;
#pragma unroll
        for (int ks = 0; ks < KSPLIT; ks++) {
            u16 u = Op[((((size_t)(qblk * KSPLIT + ks)) * 4 + w) * 128 + d) * 32 + ql];
            acc += bf2f(u) * f[ks];
        }
        Os[qin][half * 16 + i] = acc * invL;
    }
    __syncthreads();
    const size_t row0 = (size_t)qblk * 128;
#pragma unroll
    for (int j = 0; j < 16; j++) {
        int idx = tid + 256 * j;
        int q2 = idx >> 5;
        int dl = idx & 31;
        H[(row0 + q2) * D + ds0 + dl] += Os[q2][dl];
    }
}

// ---------------- final projection ----------------
__global__ __launch_bounds__(256) void final_kernel(const float* __restrict__ H,
                                                    const float* __restrict__ Wro,
                                                    const float* __restrict__ bro,
                                                    float* __restrict__ out) {
    int lane = threadIdx.x & 63;
    int tok = blockIdx.x * 4 + (threadIdx.x >> 6);
    const float* row = H + (size_t)tok * D;
    float s = row[lane] * Wro[lane] + row[lane + 64] * Wro[lane + 64];
#pragma unroll
    for (int off = 32; off; off >>= 1) s += __shfl_xor(s, off);
    if (lane == 0) out[tok] = s + bro[0];
}

extern "C" void kernel_launch(void* const* d_in, const int* in_sizes, int n_in,
                              void* d_out, int out_size, void* d_ws, size_t ws_size,
                              hipStream_t stream) {
    const int* x = (const int*)d_in[0];
    const float* pos = (const float*)d_in[1];
    const float* Wq = (const float*)d_in[2];
    const float* Wk = (const float*)d_in[3];
    const float* Wv = (const float*)d_in[4];
    const float* ln1g = (const float*)d_in[5];
    const float* ln1b = (const float*)d_in[6];
    const float* W1 = (const float*)d_in[7];
    const float* b1 = (const float*)d_in[8];
    const float* W2 = (const float*)d_in[9];
    const float* b2 = (const float*)d_in[10];
    const float* ln2g = (const float*)d_in[11];
    const float* ln2b = (const float*)d_in[12];
    const float* Wro = (const float*)d_in[13];
    const float* bro = (const float*)d_in[14];
    float* out = (float*)d_out;

    const size_t NTOK = (size_t)BATCH * T;  // 8192
    const size_t HSZ = NTOK * D;            // 1,048,576
    float* ws = (float*)d_ws;
    float* H = ws;                                   // f32 [8192][128]
    u16* Hn = (u16*)(ws + HSZ);                      // bf16 [8192][128]
    u16* qb = (u16*)(ws + HSZ + HSZ / 2);
    u16* kb = (u16*)(ws + 2 * HSZ);
    u16* vt = (u16*)(ws + 2 * HSZ + HSZ / 2);        // bf16 [B][128][2048]
    u16* mid = (u16*)(ws + 3 * HSZ);                 // bf16 [8192][512]
    u16* Op = (u16*)(ws + 5 * HSZ);                  // bf16 partials 16 MB
    float* mlbuf = ws + 9 * HSZ;                     // f32 131072
    u16* Wqkv = (u16*)(ws + 9 * HSZ + 131072);       // bf16 [L][3*128][128]
    u16* W1b = Wqkv + (size_t)NLAYER * 3 * D * D;    // bf16 [L][512][128]
    u16* W2b = W1b + (size_t)NLAYER * HMID * D;      // bf16 [L][128][512]

    const float qscale = 1.4426950408889634f / 11.313708498984761f;  // log2(e)/sqrt(D)

    conv_qkv<<<dim3(NLAYER * 3 * D * D / 256), 256, 0, stream>>>(Wq, Wk, Wv, Wqkv, qscale);
    conv_plain<<<dim3(NLAYER * HMID * D / 256), 256, 0, stream>>>(W1, W1b, NLAYER * HMID * D);
    conv_plain<<<dim3(NLAYER * HMID * D / 256), 256, 0, stream>>>(W2, W2b, NLAYER * HMID * D);
    embed_kernel<<<dim3(HSZ / 256), 256, 0, stream>>>(x, pos, H);

    for (int l = 0; l < NLAYER; l++) {
        ln_kernel<<<dim3(NTOK / 4), 256, 0, stream>>>(H, Hn, ln1g + l * D, ln1b + l * D);
        gemm_bf16<0, 0, 2, 128><<<dim3(64, 3), 256, 0, stream>>>(
            Hn, Wqkv + (size_t)l * 3 * D * D, nullptr, nullptr, qb, kb, vt, NTOK, 3 * D, D);
        attn_mfma<<<dim3(64, KSPLIT), 256, 0, stream>>>(qb, kb, vt, Op, mlbuf);
        attn_merge<<<dim3(64, 4), 256, 0, stream>>>(Op, mlbuf, H);
        ln_kernel<<<dim3(NTOK / 4), 256, 0, stream>>>(H, Hn, ln2g + l * D, ln2b + l * D);
        gemm_bf16<1, 0, 1, 128><<<dim3(64, 4), 256, 0, stream>>>(
            Hn, W1b + (size_t)l * HMID * D, b1 + (size_t)l * HMID, nullptr, mid, nullptr, nullptr, NTOK, HMID, D);
        gemm_bf16<0, 1, 0, 64><<<dim3(64, 2), 256, 0, stream>>>(
            mid, W2b + (size_t)l * D * HMID, b2 + (size_t)l * D, H, H, nullptr, nullptr, NTOK, D, HMID);
    }

    final_kernel<<<dim3(NTOK / 4), 256, 0, stream>>>(H, Wro, bro, out);
}

// Round 4
// 1017.474 us; speedup vs baseline: 5.5162x; 1.0882x over previous
//
#include <hip/hip_runtime.h>
#include <math.h>

#define D 128
#define T 2048
#define BATCH 4
#define HMID 512
#define NLAYER 12

#define KSPLIT 8
#define KPB (T / KSPLIT)   // 256 keys per block
#define BK 64
#define KS_P 136           // Ks pitch (shorts)
#define VT_P 72
#define PS_P 72

typedef unsigned short u16;
typedef __attribute__((ext_vector_type(8))) short bf16x8;
typedef __attribute__((ext_vector_type(16))) float f32x16;

__device__ inline u16 f2bf(float x) {
    unsigned u = __builtin_bit_cast(unsigned, x);
    return (u16)((u + 0x7FFFu + ((u >> 16) & 1u)) >> 16);
}
__device__ inline float bf2f(u16 v) {
    return __builtin_bit_cast(float, (unsigned)v << 16);
}

// ---------------- embedding + LN1(layer0): H f32, Hn bf16 ----------------
__global__ __launch_bounds__(256) void embed_ln(const int* __restrict__ x,
                                                const float* __restrict__ pos,
                                                const float* __restrict__ g,
                                                const float* __restrict__ bb,
                                                float* __restrict__ H,
                                                u16* __restrict__ Hn) {
    int lane = threadIdx.x & 63;
    int tok = blockIdx.x * 4 + (threadIdx.x >> 6);
    int t = tok & (T - 1);
    float xv = (float)x[tok];
    float diff = (float)lane - xv;
    float h0 = -0.5f * diff * diff + pos[(size_t)t * D + lane];
    float h1 = pos[(size_t)t * D + lane + 64];
    float* hrow = H + (size_t)tok * D;
    hrow[lane] = h0;
    hrow[lane + 64] = h1;
    float s = h0 + h1;
#pragma unroll
    for (int off = 32; off; off >>= 1) s += __shfl_xor(s, off);
    float mu = s * (1.f / D);
    float d0 = h0 - mu, d1 = h1 - mu;
    float vs = d0 * d0 + d1 * d1;
#pragma unroll
    for (int off = 32; off; off >>= 1) vs += __shfl_xor(vs, off);
    float rstd = rsqrtf(vs * (1.f / D) + 1e-5f);
    u16* orow = Hn + (size_t)tok * D;
    orow[lane] = f2bf(d0 * rstd * g[lane] + bb[lane]);
    orow[lane + 64] = f2bf(d1 * rstd * g[lane + 64] + bb[lane + 64]);
}

// ---------------- weight conversion ----------------
__global__ __launch_bounds__(256) void conv_qkv(const float* __restrict__ Wq,
                                                const float* __restrict__ Wk,
                                                const float* __restrict__ Wv,
                                                u16* __restrict__ dst, float qscale) {
    int idx = blockIdx.x * 256 + threadIdx.x;  // L*3*128*128
    int l = idx / 49152;
    int rem = idx - l * 49152;
    int s = rem >> 14;
    int off = rem & 16383;
    const float* src = (s == 0) ? Wq : ((s == 1) ? Wk : Wv);
    float v = src[l * 16384 + off] * ((s == 0) ? qscale : 1.f);
    dst[idx] = f2bf(v);
}

__global__ __launch_bounds__(256) void conv_plain(const float* __restrict__ src,
                                                  u16* __restrict__ dst, int n) {
    int idx = blockIdx.x * 256 + threadIdx.x;
    if (idx < n) dst[idx] = f2bf(src[idx]);
}

// ---------------- fused 128x128xK=128 GEMM (single barrier) ----------------
// LNPRO=1: A = LN(H f32) computed in prologue (params g/bb). LNPRO=0: A = Hn bf16.
// MODE=0: mlp1 -> gelu(A W1^T + b1) -> mid bf16 [M][512], n0 = blockIdx.y*128
// MODE=1: qkv  -> slice y: 0->q rowmajor, 1->k rowmajor, 2->v transposed per batch
template <int LNPRO, int MODE>
__global__ __launch_bounds__(256, 2) void fused_gemm(const void* __restrict__ Ain,
                                                     const u16* __restrict__ W,
                                                     const float* __restrict__ bias,
                                                     const float* __restrict__ g,
                                                     const float* __restrict__ bb,
                                                     u16* __restrict__ out0,
                                                     u16* __restrict__ outk,
                                                     u16* __restrict__ outvt,
                                                     int N) {
    __shared__ u16 As[16 * 128 * 8];
    __shared__ u16 Bs[16 * 128 * 8];
    const int tid = threadIdx.x;
    const int w = tid >> 6;
    const int l = tid & 63;
    const int h = l >> 5;
    const int ql = l & 31;
    const int wm = w >> 1;
    const int wn = w & 1;
    const int m0 = blockIdx.x * 128;
    const int n0 = blockIdx.y * 128;

    if (LNPRO) {
        const int row = tid >> 1, half = tid & 1;
        const float* hrow = (const float*)Ain + (size_t)(m0 + row) * D + half * 64;
        float4 hv[16];
        float s = 0.f;
#pragma unroll
        for (int i = 0; i < 16; i++) {
            hv[i] = *(const float4*)(hrow + i * 4);
            s += hv[i].x + hv[i].y + hv[i].z + hv[i].w;
        }
        s += __shfl_xor(s, 1);
        float mu = s * (1.f / D);
        float s2 = 0.f;
#pragma unroll
        for (int i = 0; i < 16; i++) {
            float a = hv[i].x - mu, b = hv[i].y - mu, c = hv[i].z - mu, d = hv[i].w - mu;
            s2 += a * a + b * b + c * c + d * d;
        }
        s2 += __shfl_xor(s2, 1);
        float rstd = rsqrtf(s2 * (1.f / D) + 1e-5f);
#pragma unroll
        for (int j = 0; j < 8; j++) {
            int c = half * 8 + j;
            int col = c * 8;
            u16 tmp[8];
            float4 v0 = hv[j * 2], v1 = hv[j * 2 + 1];
            tmp[0] = f2bf((v0.x - mu) * rstd * g[col + 0] + bb[col + 0]);
            tmp[1] = f2bf((v0.y - mu) * rstd * g[col + 1] + bb[col + 1]);
            tmp[2] = f2bf((v0.z - mu) * rstd * g[col + 2] + bb[col + 2]);
            tmp[3] = f2bf((v0.w - mu) * rstd * g[col + 3] + bb[col + 3]);
            tmp[4] = f2bf((v1.x - mu) * rstd * g[col + 4] + bb[col + 4]);
            tmp[5] = f2bf((v1.y - mu) * rstd * g[col + 5] + bb[col + 5]);
            tmp[6] = f2bf((v1.z - mu) * rstd * g[col + 6] + bb[col + 6]);
            tmp[7] = f2bf((v1.w - mu) * rstd * g[col + 7] + bb[col + 7]);
            *(uint4*)&As[((size_t)c * 128 + (row ^ c)) * 8] = *(uint4*)tmp;
        }
    } else {
#pragma unroll
        for (int i = 0; i < 8; i++) {
            int ci = tid + 256 * i;
            int row = ci >> 4, c = ci & 15;
            uint4 v = *(const uint4*)((const u16*)Ain + (size_t)(m0 + row) * D + c * 8);
            *(uint4*)&As[((size_t)c * 128 + (row ^ c)) * 8] = v;
        }
    }
#pragma unroll
    for (int i = 0; i < 8; i++) {
        int ci = tid + 256 * i;
        int row = ci >> 4, c = ci & 15;
        uint4 v = *(const uint4*)(W + (size_t)(n0 + row) * D + c * 8);
        *(uint4*)&Bs[((size_t)c * 128 + (row ^ c)) * 8] = v;
    }
    __syncthreads();

    f32x16 acc[2][2];
#pragma unroll
    for (int i = 0; i < 2; i++)
#pragma unroll
        for (int j = 0; j < 2; j++)
#pragma unroll
            for (int r = 0; r < 16; r++) acc[i][j][r] = 0.f;

#pragma unroll
    for (int s = 0; s < 8; s++) {
        int ch = s * 2 + h;
        bf16x8 af[2], bfr[2];
#pragma unroll
        for (int i = 0; i < 2; i++)
            af[i] = *(const bf16x8*)&As[((size_t)ch * 128 + ((wm * 64 + i * 32 + ql) ^ ch)) * 8];
#pragma unroll
        for (int j = 0; j < 2; j++)
            bfr[j] = *(const bf16x8*)&Bs[((size_t)ch * 128 + ((wn * 64 + j * 32 + ql) ^ ch)) * 8];
#pragma unroll
        for (int i = 0; i < 2; i++)
#pragma unroll
            for (int j = 0; j < 2; j++)
                acc[i][j] = __builtin_amdgcn_mfma_f32_32x32x16_bf16(af[i], bfr[j], acc[i][j], 0, 0, 0);
    }

#pragma unroll
    for (int i = 0; i < 2; i++)
#pragma unroll
        for (int j = 0; j < 2; j++) {
            const int ncl = wn * 64 + j * 32 + ql;
#pragma unroll
            for (int r = 0; r < 16; r++) {
                int mr = m0 + wm * 64 + i * 32 + 4 * h + 8 * (r >> 2) + (r & 3);
                float v = acc[i][j][r];
                if (MODE == 0) {
                    v += bias[n0 + ncl];
                    v = 0.5f * v * (1.f + erff(v * 0.7071067811865475f));
                    out0[(size_t)mr * N + n0 + ncl] = f2bf(v);
                } else {
                    int slice = blockIdx.y;
                    if (slice == 0) out0[(size_t)mr * D + ncl] = f2bf(v);
                    else if (slice == 1) outk[(size_t)mr * D + ncl] = f2bf(v);
                    else {
                        int bbk = mr >> 11, tl = mr & 2047;
                        outvt[(size_t)bbk * D * T + (size_t)ncl * T + tl] = f2bf(v);
                    }
                }
            }
        }
}

// ---------------- MLP2 + residual + LN1(next): BM=32, full D ----------------
__global__ __launch_bounds__(256, 2) void mlp2_ln(const u16* __restrict__ mid,
                                                  const u16* __restrict__ W2,
                                                  const float* __restrict__ b2,
                                                  float* __restrict__ H,
                                                  u16* __restrict__ Hn,
                                                  const float* __restrict__ g1n,
                                                  const float* __restrict__ b1n) {
    __shared__ union {
        struct { u16 As[8 * 32 * 8]; u16 Bs[8 * 128 * 8]; } st;
        struct { float Ct[32][132]; float mu[32]; float rs[32]; } ep;
    } sm;
    const int tid = threadIdx.x;
    const int l = tid & 63;
    const int h = l >> 5;
    const int ql = l & 31;
    const int wn = tid >> 6;      // 4 waves = 4 col-strips of 32
    const int m0 = blockIdx.x * 32;

    f32x16 acc;
#pragma unroll
    for (int r = 0; r < 16; r++) acc[r] = 0.f;

    for (int kb = 0; kb < 8; kb++) {
        __syncthreads();
        {
            int row = tid >> 3, c = tid & 7;  // 32 rows x 8 chunks
            uint4 v = *(const uint4*)(mid + (size_t)(m0 + row) * HMID + kb * 64 + c * 8);
            *(uint4*)&sm.st.As[((size_t)c * 32 + (row ^ c)) * 8] = v;
        }
#pragma unroll
        for (int i = 0; i < 4; i++) {
            int ci = tid + 256 * i;
            int row = ci >> 3, c = ci & 7;  // 128 rows x 8 chunks
            uint4 v = *(const uint4*)(W2 + (size_t)row * HMID + kb * 64 + c * 8);
            *(uint4*)&sm.st.Bs[((size_t)c * 128 + (row ^ c)) * 8] = v;
        }
        __syncthreads();
#pragma unroll
        for (int s = 0; s < 4; s++) {
            int ch = s * 2 + h;
            bf16x8 a0 = *(const bf16x8*)&sm.st.As[((size_t)ch * 32 + (ql ^ ch)) * 8];
            bf16x8 b0 = *(const bf16x8*)&sm.st.Bs[((size_t)ch * 128 + ((wn * 32 + ql) ^ ch)) * 8];
            acc = __builtin_amdgcn_mfma_f32_32x32x16_bf16(a0, b0, acc, 0, 0, 0);
        }
    }
    __syncthreads();
    // bias + residual -> Ct
    {
        const int col = wn * 32 + ql;
        float bv = b2[col];
#pragma unroll
        for (int r = 0; r < 16; r++) {
            int row = 4 * h + 8 * (r >> 2) + (r & 3);
            float v = acc[r] + bv + H[(size_t)(m0 + row) * D + col];
            sm.ep.Ct[row][col] = v;
        }
    }
    __syncthreads();
    // LN stats: 8 threads per row
    {
        const int q = tid >> 3, e8 = tid & 7;
        float s = 0.f;
#pragma unroll
        for (int c = 0; c < 16; c++) s += sm.ep.Ct[q][e8 * 16 + c];
        s += __shfl_xor(s, 1); s += __shfl_xor(s, 2); s += __shfl_xor(s, 4);
        float mu = s * (1.f / D);
        float s2 = 0.f;
#pragma unroll
        for (int c = 0; c < 16; c++) {
            float d0 = sm.ep.Ct[q][e8 * 16 + c] - mu;
            s2 += d0 * d0;
        }
        s2 += __shfl_xor(s2, 1); s2 += __shfl_xor(s2, 2); s2 += __shfl_xor(s2, 4);
        if (e8 == 0) {
            sm.ep.mu[q] = mu;
            sm.ep.rs[q] = rsqrtf(s2 * (1.f / D) + 1e-5f);
        }
    }
    __syncthreads();
    // coalesced write H f32 + Hn bf16 (LN1 of next layer)
    {
        const int d = tid & 127, rr = tid >> 7;
        float gv = g1n[d], bv = b1n[d];
#pragma unroll
        for (int i = 0; i < 16; i++) {
            int row = rr * 16 + i;
            float v = sm.ep.Ct[row][d];
            H[(size_t)(m0 + row) * D + d] = v;
            Hn[(size_t)(m0 + row) * D + d] = f2bf((v - sm.ep.mu[row]) * sm.ep.rs[row] * gv + bv);
        }
    }
}

// ---------------- MFMA flash attention (bf16), split-K partials ----------------
__global__ __launch_bounds__(256, 2) void attn_mfma(const u16* __restrict__ qg,
                                                    const u16* __restrict__ kg,
                                                    const u16* __restrict__ vtg,
                                                    u16* __restrict__ Op,
                                                    float* __restrict__ ml) {
    __shared__ u16 Ks[64 * KS_P];
    __shared__ u16 Vt[D * VT_P];
    __shared__ u16 Ps[4][32 * PS_P];

    const int tid = threadIdx.x;
    const int w = tid >> 6;
    const int l = tid & 63;
    const int h = l >> 5;
    const int ql = l & 31;
    const int qblk = blockIdx.x;
    const int ks = blockIdx.y;
    const int b = qblk >> 4;

    const size_t qrow = (size_t)qblk * 128 + w * 32 + ql;
    bf16x8 qf[8];
#pragma unroll
    for (int c = 0; c < 8; c++)
        qf[c] = *(const bf16x8*)(qg + qrow * D + c * 16 + h * 8);

    f32x16 ot[4];
#pragma unroll
    for (int t = 0; t < 4; t++)
#pragma unroll
        for (int r = 0; r < 16; r++) ot[t][r] = 0.f;
    float m_run = -1e30f, l_run = 0.f;

    const size_t kgb = (size_t)b * T * D;
    const size_t vtb = (size_t)b * D * T;

    for (int kt = 0; kt < KPB / BK; kt++) {
        const int kbase = ks * KPB + kt * BK;
        __syncthreads();
#pragma unroll
        for (int i = 0; i < 4; i++) {
            int ci = tid + 256 * i;
            int row = ci >> 4, cc = ci & 15;
            *(uint4*)&Ks[row * KS_P + cc * 8] =
                *(const uint4*)(kg + kgb + (size_t)(kbase + row) * D + cc * 8);
        }
#pragma unroll
        for (int i = 0; i < 4; i++) {
            int ci = tid + 256 * i;
            int dd = ci >> 3, kc = ci & 7;
            *(uint4*)&Vt[dd * VT_P + kc * 8] =
                *(const uint4*)(vtg + vtb + (size_t)dd * T + kbase + kc * 8);
        }
        __syncthreads();
        f32x16 st0, st1;
#pragma unroll
        for (int r = 0; r < 16; r++) { st0[r] = 0.f; st1[r] = 0.f; }
#pragma unroll
        for (int c = 0; c < 8; c++) {
            bf16x8 k0 = *(const bf16x8*)&Ks[(ql)*KS_P + c * 16 + h * 8];
            bf16x8 k1 = *(const bf16x8*)&Ks[(32 + ql) * KS_P + c * 16 + h * 8];
            st0 = __builtin_amdgcn_mfma_f32_32x32x16_bf16(k0, qf[c], st0, 0, 0, 0);
            st1 = __builtin_amdgcn_mfma_f32_32x32x16_bf16(k1, qf[c], st1, 0, 0, 0);
        }
        float mx = m_run;
#pragma unroll
        for (int r = 0; r < 16; r++) mx = fmaxf(mx, fmaxf(st0[r], st1[r]));
        mx = fmaxf(mx, __shfl_xor(mx, 32));
        float alpha = exp2f(m_run - mx);
        m_run = mx;
        float rs = 0.f;
#pragma unroll
        for (int r = 0; r < 16; r++) {
            float p0 = exp2f(st0[r] - mx); st0[r] = p0;
            float p1 = exp2f(st1[r] - mx); st1[r] = p1;
            rs += p0 + p1;
        }
        rs += __shfl_xor(rs, 32);
        l_run = l_run * alpha + rs;
        u16* pw = &Ps[w][ql * PS_P];
#pragma unroll
        for (int g = 0; g < 4; g++) {
            ushort4 p0, p1;
            p0.x = f2bf(st0[4 * g + 0]); p0.y = f2bf(st0[4 * g + 1]);
            p0.z = f2bf(st0[4 * g + 2]); p0.w = f2bf(st0[4 * g + 3]);
            p1.x = f2bf(st1[4 * g + 0]); p1.y = f2bf(st1[4 * g + 1]);
            p1.z = f2bf(st1[4 * g + 2]); p1.w = f2bf(st1[4 * g + 3]);
            *(ushort4*)(pw + g * 8 + h * 4) = p0;
            *(ushort4*)(pw + 32 + g * 8 + h * 4) = p1;
        }
#pragma unroll
        for (int t = 0; t < 4; t++)
#pragma unroll
            for (int r = 0; r < 16; r++) ot[t][r] *= alpha;
#pragma unroll
        for (int c = 0; c < 4; c++) {
            bf16x8 pf = *(const bf16x8*)&Ps[w][ql * PS_P + c * 16 + h * 8];
#pragma unroll
            for (int t = 0; t < 4; t++) {
                bf16x8 vf = *(const bf16x8*)&Vt[(t * 32 + ql) * VT_P + c * 16 + h * 8];
                ot[t] = __builtin_amdgcn_mfma_f32_32x32x16_bf16(vf, pf, ot[t], 0, 0, 0);
            }
        }
    }
    size_t base = (((size_t)(qblk * KSPLIT + ks)) * 4 + w) * (128 * 32);
#pragma unroll
    for (int t = 0; t < 4; t++)
#pragma unroll
        for (int r = 0; r < 16; r++) {
            int dd = (r & 3) + 8 * (r >> 2) + 4 * h + 32 * t;
            Op[base + (size_t)dd * 32 + ql] = f2bf(ot[t][r]);
        }
    if (h == 0) {
        int qi = w * 32 + ql;
        ml[(size_t)(qblk * KSPLIT + ks) * 256 + qi] = m_run;
        ml[(size_t)(qblk * KSPLIT + ks) * 256 + 128 + qi] = l_run;
    }
}

// ---------------- merge split-K partials, H += attn out ----------------
__global__ __launch_bounds__(256) void attn_merge(const u16* __restrict__ Op,
                                                  const float* __restrict__ ml,
                                                  float* __restrict__ H) {
    __shared__ float Os[128][33];
    const int qblk = blockIdx.x;
    const int ds0 = blockIdx.y * 32;
    const int tid = threadIdx.x;
    const int ql = tid & 31;
    const int w = (tid >> 5) & 3;
    const int half = tid >> 7;
    const int qin = w * 32 + ql;
    float m[KSPLIT], lv[KSPLIT];
    float M = -1e30f;
#pragma unroll
    for (int ks = 0; ks < KSPLIT; ks++) {
        m[ks] = ml[(size_t)(qblk * KSPLIT + ks) * 256 + qin];
        lv[ks] = ml[(size_t)(qblk * KSPLIT + ks) * 256 + 128 + qin];
        M = fmaxf(M, m[ks]);
    }
    float L = 0.f, f[KSPLIT];
#pragma unroll
    for (int ks = 0; ks < KSPLIT; ks++) { f[ks] = exp2f(m[ks] - M); L += lv[ks] * f[ks]; }
    float invL = 1.f / L;
#pragma unroll
    for (int i = 0; i < 16; i++) {
        int d = ds0 + half * 16 + i;
        float acc = 0.f;
#pragma unroll
        for (int ks = 0; ks < KSPLIT; ks++) {
            u16 u = Op[((((size_t)(qblk * KSPLIT + ks)) * 4 + w) * 128 + d) * 32 + ql];
            acc += bf2f(u) * f[ks];
        }
        Os[qin][half * 16 + i] = acc * invL;
    }
    __syncthreads();
    const size_t row0 = (size_t)qblk * 128;
#pragma unroll
    for (int j = 0; j < 16; j++) {
        int idx = tid + 256 * j;
        int q2 = idx >> 5;
        int dl = idx & 31;
        H[(row0 + q2) * D + ds0 + dl] += Os[q2][dl];
    }
}

// ---------------- final projection ----------------
__global__ __launch_bounds__(256) void final_kernel(const float* __restrict__ H,
                                                    const float* __restrict__ Wro,
                                                    const float* __restrict__ bro,
                                                    float* __restrict__ out) {
    int lane = threadIdx.x & 63;
    int tok = blockIdx.x * 4 + (threadIdx.x >> 6);
    const float* row = H + (size_t)tok * D;
    float s = row[lane] * Wro[lane] + row[lane + 64] * Wro[lane + 64];
#pragma unroll
    for (int off = 32; off; off >>= 1) s += __shfl_xor(s, off);
    if (lane == 0) out[tok] = s + bro[0];
}

extern "C" void kernel_launch(void* const* d_in, const int* in_sizes, int n_in,
                              void* d_out, int out_size, void* d_ws, size_t ws_size,
                              hipStream_t stream) {
    const int* x = (const int*)d_in[0];
    const float* pos = (const float*)d_in[1];
    const float* Wq = (const float*)d_in[2];
    const float* Wk = (const float*)d_in[3];
    const float* Wv = (const float*)d_in[4];
    const float* ln1g = (const float*)d_in[5];
    const float* ln1b = (const float*)d_in[6];
    const float* W1 = (const float*)d_in[7];
    const float* b1 = (const float*)d_in[8];
    const float* W2 = (const float*)d_in[9];
    const float* b2 = (const float*)d_in[10];
    const float* ln2g = (const float*)d_in[11];
    const float* ln2b = (const float*)d_in[12];
    const float* Wro = (const float*)d_in[13];
    const float* bro = (const float*)d_in[14];
    float* out = (float*)d_out;

    const size_t NTOK = (size_t)BATCH * T;  // 8192
    const size_t HSZ = NTOK * D;            // 1,048,576
    float* ws = (float*)d_ws;
    float* H = ws;                                   // f32 [8192][128]
    u16* Hn = (u16*)(ws + HSZ);                      // bf16 [8192][128]
    u16* qb = (u16*)(ws + HSZ + HSZ / 2);
    u16* kb = (u16*)(ws + 2 * HSZ);
    u16* vt = (u16*)(ws + 2 * HSZ + HSZ / 2);        // bf16 [B][128][2048]
    u16* mid = (u16*)(ws + 3 * HSZ);                 // bf16 [8192][512]
    u16* Op = (u16*)(ws + 5 * HSZ);                  // bf16 partials 16 MB
    float* mlbuf = ws + 9 * HSZ;                     // f32 131072
    u16* Wqkv = (u16*)(ws + 9 * HSZ + 131072);       // bf16 [L][3*128][128]
    u16* W1b = Wqkv + (size_t)NLAYER * 3 * D * D;    // bf16 [L][512][128]
    u16* W2b = W1b + (size_t)NLAYER * HMID * D;      // bf16 [L][128][512]

    const float qscale = 1.4426950408889634f / 11.313708498984761f;  // log2(e)/sqrt(D)

    conv_qkv<<<dim3(NLAYER * 3 * D * D / 256), 256, 0, stream>>>(Wq, Wk, Wv, Wqkv, qscale);
    conv_plain<<<dim3(NLAYER * HMID * D / 256), 256, 0, stream>>>(W1, W1b, NLAYER * HMID * D);
    conv_plain<<<dim3(NLAYER * HMID * D / 256), 256, 0, stream>>>(W2, W2b, NLAYER * HMID * D);
    embed_ln<<<dim3(NTOK / 4), 256, 0, stream>>>(x, pos, ln1g, ln1b, H, Hn);

    for (int l = 0; l < NLAYER; l++) {
        int ln = (l + 1) % NLAYER;
        fused_gemm<0, 1><<<dim3(64, 3), 256, 0, stream>>>(
            Hn, Wqkv + (size_t)l * 3 * D * D, nullptr, nullptr, nullptr, qb, kb, vt, D);
        attn_mfma<<<dim3(64, KSPLIT), 256, 0, stream>>>(qb, kb, vt, Op, mlbuf);
        attn_merge<<<dim3(64, 4), 256, 0, stream>>>(Op, mlbuf, H);
        fused_gemm<1, 0><<<dim3(64, 4), 256, 0, stream>>>(
            H, W1b + (size_t)l * HMID * D, b1 + (size_t)l * HMID,
            ln2g + (size_t)l * D, ln2b + (size_t)l * D, mid, nullptr, nullptr, HMID);
        mlp2_ln<<<dim3(256), 256, 0, stream>>>(
            mid, W2b + (size_t)l * D * HMID, b2 + (size_t)l * D, H, Hn,
            ln1g + (size_t)ln * D, ln1b + (size_t)ln * D);
    }

    final_kernel<<<dim3(NTOK / 4), 256, 0, stream>>>(H, Wro, bro, out);
}

// Round 5
// 930.040 us; speedup vs baseline: 6.0347x; 1.0940x over previous
//
#include <hip/hip_runtime.h>
#include <math.h>

#define D 128
#define T 2048
#define BATCH 4
#define HMID 512
#define NLAYER 12

#define KSPLIT 8
#define KPB (T / KSPLIT)   // 256 keys per block
#define BK 64

#if defined(__has_builtin)
#if __has_builtin(__builtin_amdgcn_global_load_lds)
#define USE_GLL 1
#endif
#endif
#ifndef USE_GLL
#define USE_GLL 0
#endif

typedef unsigned short u16;
typedef __attribute__((ext_vector_type(8))) short bf16x8;
typedef __attribute__((ext_vector_type(16))) float f32x16;

__device__ inline u16 f2bf(float x) {
    unsigned u = __builtin_bit_cast(unsigned, x);
    return (u16)((u + 0x7FFFu + ((u >> 16) & 1u)) >> 16);
}
__device__ inline float bf2f(u16 v) {
    return __builtin_bit_cast(float, (unsigned)v << 16);
}
// truncating pack of two f32 -> bf16x2 (P is in [0,1]; trunc bias < 0.4% rel)
__device__ inline unsigned pkt(float a, float b) {
    return (__builtin_bit_cast(unsigned, a) >> 16) |
           (__builtin_bit_cast(unsigned, b) & 0xFFFF0000u);
}

// ---------------- embedding + LN1(layer0): H f32, Hn1 bf16 ----------------
__global__ __launch_bounds__(256) void embed_ln(const int* __restrict__ x,
                                                const float* __restrict__ pos,
                                                const float* __restrict__ g,
                                                const float* __restrict__ bb,
                                                float* __restrict__ H,
                                                u16* __restrict__ Hn) {
    int lane = threadIdx.x & 63;
    int tok = blockIdx.x * 4 + (threadIdx.x >> 6);
    int t = tok & (T - 1);
    float xv = (float)x[tok];
    float diff = (float)lane - xv;
    float h0 = -0.5f * diff * diff + pos[(size_t)t * D + lane];
    float h1 = pos[(size_t)t * D + lane + 64];
    float* hrow = H + (size_t)tok * D;
    hrow[lane] = h0;
    hrow[lane + 64] = h1;
    float s = h0 + h1;
#pragma unroll
    for (int off = 32; off; off >>= 1) s += __shfl_xor(s, off);
    float mu = s * (1.f / D);
    float d0 = h0 - mu, d1 = h1 - mu;
    float vs = d0 * d0 + d1 * d1;
#pragma unroll
    for (int off = 32; off; off >>= 1) vs += __shfl_xor(vs, off);
    float rstd = rsqrtf(vs * (1.f / D) + 1e-5f);
    u16* orow = Hn + (size_t)tok * D;
    orow[lane] = f2bf(d0 * rstd * g[lane] + bb[lane]);
    orow[lane + 64] = f2bf(d1 * rstd * g[lane + 64] + bb[lane + 64]);
}

// ---------------- weight conversion ----------------
__global__ __launch_bounds__(256) void conv_qkv(const float* __restrict__ Wq,
                                                const float* __restrict__ Wk,
                                                const float* __restrict__ Wv,
                                                u16* __restrict__ dst, float qscale) {
    int idx = blockIdx.x * 256 + threadIdx.x;  // L*3*128*128
    int l = idx / 49152;
    int rem = idx - l * 49152;
    int s = rem >> 14;
    int off = rem & 16383;
    const float* src = (s == 0) ? Wq : ((s == 1) ? Wk : Wv);
    float v = src[l * 16384 + off] * ((s == 0) ? qscale : 1.f);
    dst[idx] = f2bf(v);
}

__global__ __launch_bounds__(256) void conv_plain(const float* __restrict__ src,
                                                  u16* __restrict__ dst, int n) {
    int idx = blockIdx.x * 256 + threadIdx.x;
    if (idx < n) dst[idx] = f2bf(src[idx]);
}

// ---------------- fused 128x128xK=128 GEMM (single barrier) ----------------
// MODE=0: mlp1 -> gelu(A W1^T + b1) -> bf16 out0 [M][N]
// MODE=1: qkv  -> slice y: 0->q rowmajor, 1->k rowmajor, 2->v transposed per batch
template <int MODE>
__global__ __launch_bounds__(256, 2) void fused_gemm(const u16* __restrict__ Ain,
                                                     const u16* __restrict__ W,
                                                     const float* __restrict__ bias,
                                                     u16* __restrict__ out0,
                                                     u16* __restrict__ outk,
                                                     u16* __restrict__ outvt,
                                                     int N) {
    __shared__ u16 As[16 * 128 * 8];
    __shared__ u16 Bs[16 * 128 * 8];
    const int tid = threadIdx.x;
    const int w = tid >> 6;
    const int l = tid & 63;
    const int h = l >> 5;
    const int ql = l & 31;
    const int wm = w >> 1;
    const int wn = w & 1;
    const int m0 = blockIdx.x * 128;
    const int n0 = blockIdx.y * 128;

#pragma unroll
    for (int i = 0; i < 8; i++) {
        int ci = tid + 256 * i;
        int row = ci >> 4, c = ci & 15;
        uint4 v = *(const uint4*)(Ain + (size_t)(m0 + row) * D + c * 8);
        *(uint4*)&As[((size_t)c * 128 + (row ^ c)) * 8] = v;
    }
#pragma unroll
    for (int i = 0; i < 8; i++) {
        int ci = tid + 256 * i;
        int row = ci >> 4, c = ci & 15;
        uint4 v = *(const uint4*)(W + (size_t)(n0 + row) * D + c * 8);
        *(uint4*)&Bs[((size_t)c * 128 + (row ^ c)) * 8] = v;
    }
    __syncthreads();

    f32x16 acc[2][2];
#pragma unroll
    for (int i = 0; i < 2; i++)
#pragma unroll
        for (int j = 0; j < 2; j++)
#pragma unroll
            for (int r = 0; r < 16; r++) acc[i][j][r] = 0.f;

#pragma unroll
    for (int s = 0; s < 8; s++) {
        int ch = s * 2 + h;
        bf16x8 af[2], bfr[2];
#pragma unroll
        for (int i = 0; i < 2; i++)
            af[i] = *(const bf16x8*)&As[((size_t)ch * 128 + ((wm * 64 + i * 32 + ql) ^ ch)) * 8];
#pragma unroll
        for (int j = 0; j < 2; j++)
            bfr[j] = *(const bf16x8*)&Bs[((size_t)ch * 128 + ((wn * 64 + j * 32 + ql) ^ ch)) * 8];
#pragma unroll
        for (int i = 0; i < 2; i++)
#pragma unroll
            for (int j = 0; j < 2; j++)
                acc[i][j] = __builtin_amdgcn_mfma_f32_32x32x16_bf16(af[i], bfr[j], acc[i][j], 0, 0, 0);
    }

#pragma unroll
    for (int i = 0; i < 2; i++)
#pragma unroll
        for (int j = 0; j < 2; j++) {
            const int ncl = wn * 64 + j * 32 + ql;
#pragma unroll
            for (int r = 0; r < 16; r++) {
                int mr = m0 + wm * 64 + i * 32 + 4 * h + 8 * (r >> 2) + (r & 3);
                float v = acc[i][j][r];
                if (MODE == 0) {
                    v += bias[n0 + ncl];
                    v = 0.5f * v * (1.f + erff(v * 0.7071067811865475f));
                    out0[(size_t)mr * N + n0 + ncl] = f2bf(v);
                } else {
                    int slice = blockIdx.y;
                    if (slice == 0) out0[(size_t)mr * D + ncl] = f2bf(v);
                    else if (slice == 1) outk[(size_t)mr * D + ncl] = f2bf(v);
                    else {
                        int bbk = mr >> 11, tl = mr & 2047;
                        outvt[(size_t)bbk * D * T + (size_t)ncl * T + tl] = f2bf(v);
                    }
                }
            }
        }
}

// ---------------- MLP2 + residual + LN1(next) [+ final proj] ----------------
__global__ __launch_bounds__(256, 2) void mlp2_ln(const u16* __restrict__ mid,
                                                  const u16* __restrict__ W2,
                                                  const float* __restrict__ b2,
                                                  float* __restrict__ H,
                                                  u16* __restrict__ Hn,
                                                  const float* __restrict__ g1n,
                                                  const float* __restrict__ b1n,
                                                  const float* __restrict__ Wro,
                                                  const float* __restrict__ bro,
                                                  float* __restrict__ outp) {
    __shared__ union {
        struct { u16 As[8 * 32 * 8]; u16 Bs[8 * 128 * 8]; } st;
        struct { float Ct[32][132]; float mu[32]; float rs[32]; } ep;
    } sm;
    const int tid = threadIdx.x;
    const int l = tid & 63;
    const int h = l >> 5;
    const int ql = l & 31;
    const int wn = tid >> 6;
    const int m0 = blockIdx.x * 32;

    f32x16 acc;
#pragma unroll
    for (int r = 0; r < 16; r++) acc[r] = 0.f;

    for (int kb = 0; kb < 8; kb++) {
        __syncthreads();
        {
            int row = tid >> 3, c = tid & 7;
            uint4 v = *(const uint4*)(mid + (size_t)(m0 + row) * HMID + kb * 64 + c * 8);
            *(uint4*)&sm.st.As[((size_t)c * 32 + (row ^ c)) * 8] = v;
        }
#pragma unroll
        for (int i = 0; i < 4; i++) {
            int ci = tid + 256 * i;
            int row = ci >> 3, c = ci & 7;
            uint4 v = *(const uint4*)(W2 + (size_t)row * HMID + kb * 64 + c * 8);
            *(uint4*)&sm.st.Bs[((size_t)c * 128 + (row ^ c)) * 8] = v;
        }
        __syncthreads();
#pragma unroll
        for (int s = 0; s < 4; s++) {
            int ch = s * 2 + h;
            bf16x8 a0 = *(const bf16x8*)&sm.st.As[((size_t)ch * 32 + (ql ^ ch)) * 8];
            bf16x8 b0 = *(const bf16x8*)&sm.st.Bs[((size_t)ch * 128 + ((wn * 32 + ql) ^ ch)) * 8];
            acc = __builtin_amdgcn_mfma_f32_32x32x16_bf16(a0, b0, acc, 0, 0, 0);
        }
    }
    __syncthreads();
    {
        const int col = wn * 32 + ql;
        float bv = b2[col];
#pragma unroll
        for (int r = 0; r < 16; r++) {
            int row = 4 * h + 8 * (r >> 2) + (r & 3);
            float v = acc[r] + bv + H[(size_t)(m0 + row) * D + col];
            sm.ep.Ct[row][col] = v;
        }
    }
    __syncthreads();
    {
        const int q = tid >> 3, e8 = tid & 7;
        float s = 0.f;
#pragma unroll
        for (int c = 0; c < 16; c++) s += sm.ep.Ct[q][e8 * 16 + c];
        s += __shfl_xor(s, 1); s += __shfl_xor(s, 2); s += __shfl_xor(s, 4);
        float mu = s * (1.f / D);
        float s2 = 0.f;
#pragma unroll
        for (int c = 0; c < 16; c++) {
            float d0 = sm.ep.Ct[q][e8 * 16 + c] - mu;
            s2 += d0 * d0;
        }
        s2 += __shfl_xor(s2, 1); s2 += __shfl_xor(s2, 2); s2 += __shfl_xor(s2, 4);
        if (e8 == 0) {
            sm.ep.mu[q] = mu;
            sm.ep.rs[q] = rsqrtf(s2 * (1.f / D) + 1e-5f);
        }
    }
    __syncthreads();
    {
        const int d = tid & 127, rr = tid >> 7;
        float gv = g1n[d], bv = b1n[d];
#pragma unroll
        for (int i = 0; i < 16; i++) {
            int row = rr * 16 + i;
            float v = sm.ep.Ct[row][d];
            H[(size_t)(m0 + row) * D + d] = v;
            Hn[(size_t)(m0 + row) * D + d] = f2bf((v - sm.ep.mu[row]) * sm.ep.rs[row] * gv + bv);
        }
    }
    if (outp) {  // last layer: out[tok] = H row . Wro + bro
        const int q = tid >> 3, e8 = tid & 7;
        float s = 0.f;
#pragma unroll
        for (int c = 0; c < 16; c++) s += sm.ep.Ct[q][e8 * 16 + c] * Wro[e8 * 16 + c];
        s += __shfl_xor(s, 1); s += __shfl_xor(s, 2); s += __shfl_xor(s, 4);
        if (e8 == 0) outp[m0 + q] = s + bro[0];
    }
}

// ---------------- MFMA flash attention: swizzled LDS, async staging, P via shfl --------
// LDS layouts (pad-free, XOR-swizzled by low 3 bits of row):
//   Ks[row 64][chunk16 of 8 shorts], phys chunk = ch ^ (row&7)
//   Vt[d 128][chunk8 of 8 shorts],  phys chunk = ch ^ (d&7)
__global__ __launch_bounds__(256, 2) void attn_mfma(const u16* __restrict__ qg,
                                                    const u16* __restrict__ kg,
                                                    const u16* __restrict__ vtg,
                                                    u16* __restrict__ Op,
                                                    float* __restrict__ ml) {
    __shared__ u16 Ks[64 * 128];
    __shared__ u16 Vt[128 * 64];
    const int tid = threadIdx.x;
    const int w = tid >> 6;
    const int l = tid & 63;
    const int h = l >> 5;
    const int ql = l & 31;
    const int qblk = blockIdx.x;
    const int ks = blockIdx.y;
    const int b = qblk >> 4;

    const size_t qrow = (size_t)qblk * 128 + w * 32 + ql;
    bf16x8 qf[8];
#pragma unroll
    for (int c = 0; c < 8; c++)
        qf[c] = *(const bf16x8*)(qg + qrow * D + c * 16 + h * 8);

    f32x16 ot[4];
#pragma unroll
    for (int t = 0; t < 4; t++)
#pragma unroll
        for (int r = 0; r < 16; r++) ot[t][r] = 0.f;
    float m_run = -1e30f, l_run = 0.f;

    const size_t kgb = (size_t)b * T * D;
    const size_t vtb = (size_t)b * D * T;

    for (int kt = 0; kt < KPB / BK; kt++) {
        const int kbase = ks * KPB + kt * BK;
        __syncthreads();
#if USE_GLL
#pragma unroll
        for (int i = 0; i < 4; i++) {
            int s = w * 256 + i * 64 + l;
            int row = s >> 4, ch = (s & 15) ^ (row & 7);
            __builtin_amdgcn_global_load_lds(
                (const __attribute__((address_space(1))) void*)(kg + kgb + (size_t)(kbase + row) * D + ch * 8),
                (__attribute__((address_space(3))) void*)&Ks[(w * 256 + i * 64) * 8], 16, 0, 0);
        }
#pragma unroll
        for (int i = 0; i < 4; i++) {
            int s = w * 256 + i * 64 + l;
            int dd = s >> 3, ch = (s & 7) ^ (dd & 7);
            __builtin_amdgcn_global_load_lds(
                (const __attribute__((address_space(1))) void*)(vtg + vtb + (size_t)dd * T + kbase + ch * 8),
                (__attribute__((address_space(3))) void*)&Vt[(w * 256 + i * 64) * 8], 16, 0, 0);
        }
#else
#pragma unroll
        for (int i = 0; i < 4; i++) {
            int s = tid + i * 256;
            int row = s >> 4, ch = (s & 15) ^ (row & 7);
            *(uint4*)&Ks[(size_t)s * 8] = *(const uint4*)(kg + kgb + (size_t)(kbase + row) * D + ch * 8);
            int dd = s >> 3, ch2 = (s & 7) ^ (dd & 7);
            *(uint4*)&Vt[(size_t)s * 8] = *(const uint4*)(vtg + vtb + (size_t)dd * T + kbase + ch2 * 8);
        }
#endif
        __syncthreads();
        // S^T = K * Q^T
        f32x16 st0, st1;
#pragma unroll
        for (int r = 0; r < 16; r++) { st0[r] = 0.f; st1[r] = 0.f; }
#pragma unroll
        for (int c = 0; c < 8; c++) {
            int ch = c * 2 + h;
            bf16x8 k0 = *(const bf16x8*)&Ks[(ql * 16 + (ch ^ (ql & 7))) * 8];
            bf16x8 k1 = *(const bf16x8*)&Ks[((32 + ql) * 16 + (ch ^ (ql & 7))) * 8];
            st0 = __builtin_amdgcn_mfma_f32_32x32x16_bf16(k0, qf[c], st0, 0, 0, 0);
            st1 = __builtin_amdgcn_mfma_f32_32x32x16_bf16(k1, qf[c], st1, 0, 0, 0);
        }
        // online softmax (exp2 domain), per-lane q stats
        float mx = m_run;
#pragma unroll
        for (int r = 0; r < 16; r++) mx = fmaxf(mx, fmaxf(st0[r], st1[r]));
        mx = fmaxf(mx, __shfl_xor(mx, 32));
        float alpha = exp2f(m_run - mx);
        m_run = mx;
        float rs = 0.f;
#pragma unroll
        for (int r = 0; r < 16; r++) {
            float p0 = exp2f(st0[r] - mx); st0[r] = p0;
            float p1 = exp2f(st1[r] - mx); st1[r] = p1;
            rs += p0 + p1;
        }
        rs += __shfl_xor(rs, 32);
        l_run = l_run * alpha + rs;
        // pack P groups: pk[t][g] = keys {4h_src+8g+0..3} as bf16x4
        uint2 pk0[4], pk1[4];
#pragma unroll
        for (int g = 0; g < 4; g++) {
            pk0[g].x = pkt(st0[4 * g + 0], st0[4 * g + 1]);
            pk0[g].y = pkt(st0[4 * g + 2], st0[4 * g + 3]);
            pk1[g].x = pkt(st1[4 * g + 0], st1[4 * g + 1]);
            pk1[g].y = pkt(st1[4 * g + 2], st1[4 * g + 3]);
        }
#pragma unroll
        for (int t = 0; t < 4; t++)
#pragma unroll
            for (int r = 0; r < 16; r++) ot[t][r] *= alpha;
        // O^T += V^T * P^T ; build P B-fragments via h-exchange (shfl_xor 32)
#pragma unroll
        for (int c = 0; c < 4; c++) {
            const uint2* pk = (c < 2) ? pk0 : pk1;
            const int cc = c & 1;
            uint2 own = h ? pk[2 * cc + 1] : pk[2 * cc];
            uint2 snd = h ? pk[2 * cc] : pk[2 * cc + 1];
            uint2 rcv;
            rcv.x = (unsigned)__shfl_xor((int)snd.x, 32);
            rcv.y = (unsigned)__shfl_xor((int)snd.y, 32);
            uint4 fr;
            fr.x = h ? rcv.x : own.x;
            fr.y = h ? rcv.y : own.y;
            fr.z = h ? own.x : rcv.x;
            fr.w = h ? own.y : rcv.y;
            bf16x8 pf = __builtin_bit_cast(bf16x8, fr);
            int ch = c * 2 + h;
#pragma unroll
            for (int t = 0; t < 4; t++) {
                bf16x8 vf = *(const bf16x8*)&Vt[((t * 32 + ql) * 8 + (ch ^ (ql & 7))) * 8];
                ot[t] = __builtin_amdgcn_mfma_f32_32x32x16_bf16(vf, pf, ot[t], 0, 0, 0);
            }
        }
    }
    // partials: Op [qblk][ks][w][d 128][q 32] bf16
    size_t base = (((size_t)(qblk * KSPLIT + ks)) * 4 + w) * (128 * 32);
#pragma unroll
    for (int t = 0; t < 4; t++)
#pragma unroll
        for (int r = 0; r < 16; r++) {
            int dd = (r & 3) + 8 * (r >> 2) + 4 * h + 32 * t;
            Op[base + (size_t)dd * 32 + ql] = f2bf(ot[t][r]);
        }
    if (h == 0) {
        int qi = w * 32 + ql;
        ml[(size_t)(qblk * KSPLIT + ks) * 256 + qi] = m_run;
        ml[(size_t)(qblk * KSPLIT + ks) * 256 + 128 + qi] = l_run;
    }
}

// ---------------- merge split-K + residual + LN2: writes H, Hn2 ----------------
// grid 256: block = (qblk = bid>>2, w = bid&3) -> 32 q rows, full D
__global__ __launch_bounds__(256) void attn_merge_ln(const u16* __restrict__ Op,
                                                     const float* __restrict__ ml,
                                                     float* __restrict__ H,
                                                     u16* __restrict__ Hn2,
                                                     const float* __restrict__ g2,
                                                     const float* __restrict__ b2l) {
    __shared__ float Os[32][132];
    __shared__ float mu_s[32], rs_s[32];
    const int tid = threadIdx.x;
    const int qblk = blockIdx.x >> 2;
    const int w = blockIdx.x & 3;
    const int qbase = qblk * 128 + w * 32;
    const int ql = tid & 31;
    const int dg = tid >> 5;  // 0..7

    float m[KSPLIT], lv[KSPLIT];
    float M = -1e30f;
#pragma unroll
    for (int ks = 0; ks < KSPLIT; ks++) {
        m[ks] = ml[(size_t)(qblk * KSPLIT + ks) * 256 + w * 32 + ql];
        lv[ks] = ml[(size_t)(qblk * KSPLIT + ks) * 256 + 128 + w * 32 + ql];
        M = fmaxf(M, m[ks]);
    }
    float L = 0.f, f[KSPLIT];
#pragma unroll
    for (int ks = 0; ks < KSPLIT; ks++) { f[ks] = exp2f(m[ks] - M); L += lv[ks] * f[ks]; }
    float invL = 1.f / L;

    float acc[16];
#pragma unroll
    for (int i = 0; i < 16; i++) acc[i] = 0.f;
#pragma unroll
    for (int ks = 0; ks < KSPLIT; ks++) {
        size_t base = (((size_t)(qblk * KSPLIT + ks)) * 4 + w) * (128 * 32);
#pragma unroll
        for (int i = 0; i < 16; i++)
            acc[i] += bf2f(Op[base + (size_t)(dg * 16 + i) * 32 + ql]) * f[ks];
    }
#pragma unroll
    for (int i = 0; i < 16; i++) Os[ql][dg * 16 + i] = acc[i] * invL;
    __syncthreads();
    // residual: v = H_old + attn_out -> Os, H
    {
        const int d = tid & 127, rr = tid >> 7;
#pragma unroll
        for (int i = 0; i < 16; i++) {
            int row = rr * 16 + i;
            float v = Os[row][d] + H[(size_t)(qbase + row) * D + d];
            Os[row][d] = v;
            H[(size_t)(qbase + row) * D + d] = v;
        }
    }
    __syncthreads();
    // LN2 stats
    {
        const int q = tid >> 3, e8 = tid & 7;
        float s = 0.f;
#pragma unroll
        for (int c = 0; c < 16; c++) s += Os[q][e8 * 16 + c];
        s += __shfl_xor(s, 1); s += __shfl_xor(s, 2); s += __shfl_xor(s, 4);
        float mu = s * (1.f / D);
        float s2 = 0.f;
#pragma unroll
        for (int c = 0; c < 16; c++) {
            float d0 = Os[q][e8 * 16 + c] - mu;
            s2 += d0 * d0;
        }
        s2 += __shfl_xor(s2, 1); s2 += __shfl_xor(s2, 2); s2 += __shfl_xor(s2, 4);
        if (e8 == 0) { mu_s[q] = mu; rs_s[q] = rsqrtf(s2 * (1.f / D) + 1e-5f); }
    }
    __syncthreads();
    {
        const int d = tid & 127, rr = tid >> 7;
        float gv = g2[d], bv = b2l[d];
#pragma unroll
        for (int i = 0; i < 16; i++) {
            int row = rr * 16 + i;
            Hn2[(size_t)(qbase + row) * D + d] =
                f2bf((Os[row][d] - mu_s[row]) * rs_s[row] * gv + bv);
        }
    }
}

extern "C" void kernel_launch(void* const* d_in, const int* in_sizes, int n_in,
                              void* d_out, int out_size, void* d_ws, size_t ws_size,
                              hipStream_t stream) {
    const int* x = (const int*)d_in[0];
    const float* pos = (const float*)d_in[1];
    const float* Wq = (const float*)d_in[2];
    const float* Wk = (const float*)d_in[3];
    const float* Wv = (const float*)d_in[4];
    const float* ln1g = (const float*)d_in[5];
    const float* ln1b = (const float*)d_in[6];
    const float* W1 = (const float*)d_in[7];
    const float* b1 = (const float*)d_in[8];
    const float* W2 = (const float*)d_in[9];
    const float* b2 = (const float*)d_in[10];
    const float* ln2g = (const float*)d_in[11];
    const float* ln2b = (const float*)d_in[12];
    const float* Wro = (const float*)d_in[13];
    const float* bro = (const float*)d_in[14];
    float* out = (float*)d_out;

    const size_t NTOK = (size_t)BATCH * T;  // 8192
    const size_t HSZ = NTOK * D;            // 1,048,576
    float* ws = (float*)d_ws;
    float* H = ws;                                   // f32 [8192][128]
    u16* Hn1 = (u16*)(ws + HSZ);                     // bf16 [8192][128] (LN1 out)
    u16* qb = (u16*)(ws + HSZ + HSZ / 2);
    u16* kb = (u16*)(ws + 2 * HSZ);
    u16* vt = (u16*)(ws + 2 * HSZ + HSZ / 2);        // bf16 [B][128][2048]
    u16* Hn2 = (u16*)(ws + 3 * HSZ);                 // bf16 [8192][128] (LN2 out)
    u16* mid = (u16*)(ws + 3 * HSZ + HSZ / 2);       // bf16 [8192][512]
    u16* Op = (u16*)(ws + 6 * HSZ);                  // bf16 partials 16 MB
    float* mlbuf = ws + 10 * HSZ;                    // f32 131072
    u16* Wqkv = (u16*)(ws + 10 * HSZ + 131072);      // bf16 [L][3*128][128]
    u16* W1b = Wqkv + (size_t)NLAYER * 3 * D * D;
    u16* W2b = W1b + (size_t)NLAYER * HMID * D;

    const float qscale = 1.4426950408889634f / 11.313708498984761f;  // log2(e)/sqrt(D)

    conv_qkv<<<dim3(NLAYER * 3 * D * D / 256), 256, 0, stream>>>(Wq, Wk, Wv, Wqkv, qscale);
    conv_plain<<<dim3(NLAYER * HMID * D / 256), 256, 0, stream>>>(W1, W1b, NLAYER * HMID * D);
    conv_plain<<<dim3(NLAYER * HMID * D / 256), 256, 0, stream>>>(W2, W2b, NLAYER * HMID * D);
    embed_ln<<<dim3(NTOK / 4), 256, 0, stream>>>(x, pos, ln1g, ln1b, H, Hn1);

    for (int l = 0; l < NLAYER; l++) {
        int ln = (l + 1) % NLAYER;
        bool last = (l == NLAYER - 1);
        fused_gemm<1><<<dim3(64, 3), 256, 0, stream>>>(
            Hn1, Wqkv + (size_t)l * 3 * D * D, nullptr, qb, kb, vt, D);
        attn_mfma<<<dim3(64, KSPLIT), 256, 0, stream>>>(qb, kb, vt, Op, mlbuf);
        attn_merge_ln<<<dim3(256), 256, 0, stream>>>(
            Op, mlbuf, H, Hn2, ln2g + (size_t)l * D, ln2b + (size_t)l * D);
        fused_gemm<0><<<dim3(64, 4), 256, 0, stream>>>(
            Hn2, W1b + (size_t)l * HMID * D, b1 + (size_t)l * HMID, mid, nullptr, nullptr, HMID);
        mlp2_ln<<<dim3(256), 256, 0, stream>>>(
            mid, W2b + (size_t)l * D * HMID, b2 + (size_t)l * D, H, Hn1,
            ln1g + (size_t)ln * D, ln1b + (size_t)ln * D,
            Wro, bro, last ? out : nullptr);
    }
}

// Round 6
// 633.386 us; speedup vs baseline: 8.8612x; 1.4684x over previous
//
#include <hip/hip_runtime.h>
#include <math.h>

#define D 128
#define T 2048
#define BATCH 4
#define HMID 512
#define NLAYER 12

#define KSPLIT 8
#define KPB (T / KSPLIT)   // 256 keys per attn block
#define BK 64

#if defined(__has_builtin)
#if __has_builtin(__builtin_amdgcn_global_load_lds)
#define USE_GLL 1
#endif
#endif
#ifndef USE_GLL
#define USE_GLL 0
#endif

typedef unsigned short u16;
typedef __attribute__((ext_vector_type(8))) short bf16x8;
typedef __attribute__((ext_vector_type(16))) float f32x16;

__device__ inline u16 f2bf(float x) {
    unsigned u = __builtin_bit_cast(unsigned, x);
    return (u16)((u + 0x7FFFu + ((u >> 16) & 1u)) >> 16);
}
__device__ inline float bf2f(u16 v) {
    return __builtin_bit_cast(float, (unsigned)v << 16);
}
// truncating pack of two f32 -> bf16x2 (P in [0,1], trunc bias <0.4% rel)
__device__ inline unsigned pkt(float a, float b) {
    return (__builtin_bit_cast(unsigned, a) >> 16) |
           (__builtin_bit_cast(unsigned, b) & 0xFFFF0000u);
}

// ================= shared device helpers (32-row blocks) =================
// Ct: [32][133] f32 work rows. As: 16 chunks x 32 rows x 8 shorts (swizzled).
// Wst: 16 chunks x 128 rows x 8 shorts (swizzled).

__device__ inline void ln_stats32(const float (*Ct)[133], float* mu_s, float* rs_s, int tid) {
    const int q = tid >> 3, e8 = tid & 7;
    float s = 0.f;
#pragma unroll
    for (int c = 0; c < 16; c++) s += Ct[q][e8 * 16 + c];
    s += __shfl_xor(s, 1); s += __shfl_xor(s, 2); s += __shfl_xor(s, 4);
    float mu = s * (1.f / D);
    float s2 = 0.f;
#pragma unroll
    for (int c = 0; c < 16; c++) {
        float d0 = Ct[q][e8 * 16 + c] - mu;
        s2 += d0 * d0;
    }
    s2 += __shfl_xor(s2, 1); s2 += __shfl_xor(s2, 2); s2 += __shfl_xor(s2, 4);
    if (e8 == 0) { mu_s[q] = mu; rs_s[q] = rsqrtf(s2 * (1.f / D) + 1e-5f); }
}

__device__ inline void build_as(const float (*Ct)[133], const float* mu_s, const float* rs_s,
                                const float* __restrict__ g, const float* __restrict__ bb,
                                u16* As, int tid) {
    const int row = tid >> 3, e8 = tid & 7;
    const float mu = mu_s[row], rs = rs_s[row];
#pragma unroll
    for (int cc = 0; cc < 2; cc++) {
        int c = e8 * 2 + cc;
        u16 tmp[8];
#pragma unroll
        for (int j = 0; j < 8; j++) {
            int d = c * 8 + j;
            tmp[j] = f2bf((Ct[row][d] - mu) * rs * g[d] + bb[d]);
        }
        *(uint4*)&As[((size_t)c * 32 + (row ^ (c & 7))) * 8] = *(uint4*)tmp;
    }
}

// stage 128 rows x 128 cols bf16 into Wst (chunk-swizzled)
__device__ inline void stage_w(const u16* __restrict__ W, int ldw, u16* Wst, int tid) {
#pragma unroll
    for (int i = 0; i < 8; i++) {
        int ci = tid + 256 * i;
        int row = ci >> 4, c = ci & 15;
        *(uint4*)&Wst[((size_t)c * 128 + (row ^ c)) * 8] =
            *(const uint4*)(W + (size_t)row * ldw + c * 8);
    }
}

// C[32 rows(reg)][128 n(lane, wave-strips)] = As(32xK128) @ Wst^T
__device__ inline f32x16 mm_32x128(const u16* As, const u16* Wst, int wv, int ql, int h) {
    f32x16 a;
#pragma unroll
    for (int r = 0; r < 16; r++) a[r] = 0.f;
#pragma unroll
    for (int s = 0; s < 8; s++) {
        int ch = 2 * s + h;
        bf16x8 af = *(const bf16x8*)&As[((size_t)ch * 32 + (ql ^ (ch & 7))) * 8];
        bf16x8 bf = *(const bf16x8*)&Wst[((size_t)ch * 128 + ((wv * 32 + ql) ^ ch)) * 8];
        a = __builtin_amdgcn_mfma_f32_32x32x16_bf16(af, bf, a, 0, 0, 0);
    }
    return a;
}

// QKV projection for this block's 32 rows (As must hold LN1 rows)
__device__ inline void qkv_phase(const u16* As, const u16* __restrict__ Wqkvl, u16* Wst,
                                 u16* __restrict__ qb, u16* __restrict__ kb,
                                 u16* __restrict__ vt, int m0, int tid) {
    const int wv = tid >> 6, l = tid & 63, h = l >> 5, ql = l & 31;
    const int bbk = m0 >> 11;
    const int tl0 = m0 & 2047;
#pragma unroll
    for (int sl = 0; sl < 3; sl++) {
        __syncthreads();
        stage_w(Wqkvl + (size_t)sl * 128 * D, D, Wst, tid);
        __syncthreads();
        f32x16 a = mm_32x128(As, Wst, wv, ql, h);
        const int n = wv * 32 + ql;
        if (sl == 2) {
            u16* dst = vt + (size_t)bbk * D * T + (size_t)n * T + tl0;
#pragma unroll
            for (int g = 0; g < 4; g++) {
                ushort4 o;
                o.x = f2bf(a[4 * g + 0]);
                o.y = f2bf(a[4 * g + 1]);
                o.z = f2bf(a[4 * g + 2]);
                o.w = f2bf(a[4 * g + 3]);
                *(ushort4*)(dst + 8 * g + 4 * h) = o;
            }
        } else {
            u16* dst = (sl == 0) ? qb : kb;
#pragma unroll
            for (int r = 0; r < 16; r++) {
                int row = (r & 3) + 8 * (r >> 2) + 4 * h;
                dst[(size_t)(m0 + row) * D + n] = f2bf(a[r]);
            }
        }
    }
}

// ================= weight conversion (one dispatch) =================
__global__ __launch_bounds__(256) void conv_all(const float* __restrict__ Wq,
                                                const float* __restrict__ Wk,
                                                const float* __restrict__ Wv,
                                                const float* __restrict__ W1,
                                                const float* __restrict__ W2,
                                                u16* __restrict__ Wqkv,
                                                u16* __restrict__ W1b,
                                                u16* __restrict__ W2b, float qscale) {
    const int NQ = NLAYER * 3 * D * D;
    const int NW = NLAYER * HMID * D;
    int idx = blockIdx.x * 256 + threadIdx.x;
    if (idx < NQ) {
        int lN = idx / (3 * D * D);
        int rem = idx - lN * (3 * D * D);
        int s = rem >> 14;
        int off = rem & 16383;
        const float* src = (s == 0) ? Wq : ((s == 1) ? Wk : Wv);
        Wqkv[idx] = f2bf(src[lN * 16384 + off] * ((s == 0) ? qscale : 1.f));
    } else if (idx < NQ + NW) {
        W1b[idx - NQ] = f2bf(W1[idx - NQ]);
    } else if (idx < NQ + 2 * NW) {
        W2b[idx - NQ - NW] = f2bf(W2[idx - NQ - NW]);
    }
}

// ================= embed + LN1 + QKV (layer 0 prologue) =================
__global__ __launch_bounds__(256, 1) void embed_qkv(const int* __restrict__ x,
                                                    const float* __restrict__ pos,
                                                    const float* __restrict__ g1,
                                                    const float* __restrict__ b1g,
                                                    const u16* __restrict__ Wqkv0,
                                                    u16* __restrict__ qb, u16* __restrict__ kb,
                                                    u16* __restrict__ vt,
                                                    float* __restrict__ H) {
    __shared__ float Ct[32][133];
    __shared__ float mu_s[32], rs_s[32];
    __shared__ u16 As[16 * 32 * 8];
    __shared__ u16 Wst[16 * 128 * 8];
    const int tid = threadIdx.x;
    const int m0 = blockIdx.x * 32;
    {
        const int d = tid & 127, rr = tid >> 7;
#pragma unroll
        for (int i = 0; i < 16; i++) {
            int row = rr * 16 + i;
            int tok = m0 + row;
            int t = tok & (T - 1);
            float e = 0.f;
            if (d < 64) {
                float diff = (float)d - (float)x[tok];
                e = -0.5f * diff * diff;
            }
            float v = e + pos[(size_t)t * D + d];
            Ct[row][d] = v;
            H[(size_t)tok * D + d] = v;
        }
    }
    __syncthreads();
    ln_stats32(Ct, mu_s, rs_s, tid);
    __syncthreads();
    build_as(Ct, mu_s, rs_s, g1, b1g, As, tid);
    qkv_phase(As, Wqkv0, Wst, qb, kb, vt, m0, tid);
}

// ================= MFMA flash attention (unchanged from R5) =================
__global__ __launch_bounds__(256, 2) void attn_mfma(const u16* __restrict__ qg,
                                                    const u16* __restrict__ kg,
                                                    const u16* __restrict__ vtg,
                                                    u16* __restrict__ Op,
                                                    float* __restrict__ ml) {
    __shared__ u16 Ks[64 * 128];
    __shared__ u16 Vt[128 * 64];
    const int tid = threadIdx.x;
    const int w = tid >> 6;
    const int l = tid & 63;
    const int h = l >> 5;
    const int ql = l & 31;
    const int qblk = blockIdx.x;
    const int ks = blockIdx.y;
    const int b = qblk >> 4;

    const size_t qrow = (size_t)qblk * 128 + w * 32 + ql;
    bf16x8 qf[8];
#pragma unroll
    for (int c = 0; c < 8; c++)
        qf[c] = *(const bf16x8*)(qg + qrow * D + c * 16 + h * 8);

    f32x16 ot[4];
#pragma unroll
    for (int t = 0; t < 4; t++)
#pragma unroll
        for (int r = 0; r < 16; r++) ot[t][r] = 0.f;
    float m_run = -1e30f, l_run = 0.f;

    const size_t kgb = (size_t)b * T * D;
    const size_t vtb = (size_t)b * D * T;

    for (int kt = 0; kt < KPB / BK; kt++) {
        const int kbase = ks * KPB + kt * BK;
        __syncthreads();
#if USE_GLL
#pragma unroll
        for (int i = 0; i < 4; i++) {
            int s = w * 256 + i * 64 + l;
            int row = s >> 4, ch = (s & 15) ^ (row & 7);
            __builtin_amdgcn_global_load_lds(
                (const __attribute__((address_space(1))) void*)(kg + kgb + (size_t)(kbase + row) * D + ch * 8),
                (__attribute__((address_space(3))) void*)&Ks[(w * 256 + i * 64) * 8], 16, 0, 0);
        }
#pragma unroll
        for (int i = 0; i < 4; i++) {
            int s = w * 256 + i * 64 + l;
            int dd = s >> 3, ch = (s & 7) ^ (dd & 7);
            __builtin_amdgcn_global_load_lds(
                (const __attribute__((address_space(1))) void*)(vtg + vtb + (size_t)dd * T + kbase + ch * 8),
                (__attribute__((address_space(3))) void*)&Vt[(w * 256 + i * 64) * 8], 16, 0, 0);
        }
#else
#pragma unroll
        for (int i = 0; i < 4; i++) {
            int s = tid + i * 256;
            int row = s >> 4, ch = (s & 15) ^ (row & 7);
            *(uint4*)&Ks[(size_t)s * 8] = *(const uint4*)(kg + kgb + (size_t)(kbase + row) * D + ch * 8);
            int dd = s >> 3, ch2 = (s & 7) ^ (dd & 7);
            *(uint4*)&Vt[(size_t)s * 8] = *(const uint4*)(vtg + vtb + (size_t)dd * T + kbase + ch2 * 8);
        }
#endif
        __syncthreads();
        f32x16 st0, st1;
#pragma unroll
        for (int r = 0; r < 16; r++) { st0[r] = 0.f; st1[r] = 0.f; }
#pragma unroll
        for (int c = 0; c < 8; c++) {
            int ch = c * 2 + h;
            bf16x8 k0 = *(const bf16x8*)&Ks[(ql * 16 + (ch ^ (ql & 7))) * 8];
            bf16x8 k1 = *(const bf16x8*)&Ks[((32 + ql) * 16 + (ch ^ (ql & 7))) * 8];
            st0 = __builtin_amdgcn_mfma_f32_32x32x16_bf16(k0, qf[c], st0, 0, 0, 0);
            st1 = __builtin_amdgcn_mfma_f32_32x32x16_bf16(k1, qf[c], st1, 0, 0, 0);
        }
        float mx = m_run;
#pragma unroll
        for (int r = 0; r < 16; r++) mx = fmaxf(mx, fmaxf(st0[r], st1[r]));
        mx = fmaxf(mx, __shfl_xor(mx, 32));
        float alpha = exp2f(m_run - mx);
        m_run = mx;
        float rs = 0.f;
#pragma unroll
        for (int r = 0; r < 16; r++) {
            float p0 = exp2f(st0[r] - mx); st0[r] = p0;
            float p1 = exp2f(st1[r] - mx); st1[r] = p1;
            rs += p0 + p1;
        }
        rs += __shfl_xor(rs, 32);
        l_run = l_run * alpha + rs;
        uint2 pk0[4], pk1[4];
#pragma unroll
        for (int g = 0; g < 4; g++) {
            pk0[g].x = pkt(st0[4 * g + 0], st0[4 * g + 1]);
            pk0[g].y = pkt(st0[4 * g + 2], st0[4 * g + 3]);
            pk1[g].x = pkt(st1[4 * g + 0], st1[4 * g + 1]);
            pk1[g].y = pkt(st1[4 * g + 2], st1[4 * g + 3]);
        }
#pragma unroll
        for (int t = 0; t < 4; t++)
#pragma unroll
            for (int r = 0; r < 16; r++) ot[t][r] *= alpha;
#pragma unroll
        for (int c = 0; c < 4; c++) {
            const uint2* pk = (c < 2) ? pk0 : pk1;
            const int cc = c & 1;
            uint2 own = h ? pk[2 * cc + 1] : pk[2 * cc];
            uint2 snd = h ? pk[2 * cc] : pk[2 * cc + 1];
            uint2 rcv;
            rcv.x = (unsigned)__shfl_xor((int)snd.x, 32);
            rcv.y = (unsigned)__shfl_xor((int)snd.y, 32);
            uint4 fr;
            fr.x = h ? rcv.x : own.x;
            fr.y = h ? rcv.y : own.y;
            fr.z = h ? own.x : rcv.x;
            fr.w = h ? own.y : rcv.y;
            bf16x8 pf = __builtin_bit_cast(bf16x8, fr);
            int ch = c * 2 + h;
#pragma unroll
            for (int t = 0; t < 4; t++) {
                bf16x8 vf = *(const bf16x8*)&Vt[((t * 32 + ql) * 8 + (ch ^ (ql & 7))) * 8];
                ot[t] = __builtin_amdgcn_mfma_f32_32x32x16_bf16(vf, pf, ot[t], 0, 0, 0);
            }
        }
    }
    size_t base = (((size_t)(qblk * KSPLIT + ks)) * 4 + w) * (128 * 32);
#pragma unroll
    for (int t = 0; t < 4; t++)
#pragma unroll
        for (int r = 0; r < 16; r++) {
            int dd = (r & 3) + 8 * (r >> 2) + 4 * h + 32 * t;
            Op[base + (size_t)dd * 32 + ql] = f2bf(ot[t][r]);
        }
    if (h == 0) {
        int qi = w * 32 + ql;
        ml[(size_t)(qblk * KSPLIT + ks) * 256 + qi] = m_run;
        ml[(size_t)(qblk * KSPLIT + ks) * 256 + 128 + qi] = l_run;
    }
}

// ====== layer tail: merge + resid + LN2 + MLP1 + MLP2 + resid + LN1' + QKV' ======
// grid 256 blocks x 32 rows. LAST: final projection instead of LN1'/QKV'.
template <int LAST>
__global__ __launch_bounds__(256, 1) void layer_tail(
    const u16* __restrict__ Op, const float* __restrict__ ml,
    float* __restrict__ H,
    const float* __restrict__ g2, const float* __restrict__ b2l,
    const u16* __restrict__ W1l, const float* __restrict__ b1l,
    const u16* __restrict__ W2l, const float* __restrict__ b2bias,
    const float* __restrict__ g1n, const float* __restrict__ b1n,
    const u16* __restrict__ Wqkvn,
    u16* __restrict__ qb, u16* __restrict__ kb, u16* __restrict__ vt,
    const float* __restrict__ Wro, const float* __restrict__ bro,
    float* __restrict__ outp) {
    __shared__ float Ct[32][133];
    __shared__ float mu_s[32], rs_s[32];
    __shared__ u16 As[16 * 32 * 8];
    __shared__ u16 midS[64 * 32 * 8];
    __shared__ u16 Wst[16 * 128 * 8];

    const int tid = threadIdx.x;
    const int bid = blockIdx.x;
    const int qblk = bid >> 2;
    const int wq = bid & 3;
    const int m0 = bid * 32;
    const int wv = tid >> 6;
    const int l = tid & 63;
    const int h = l >> 5;
    const int ql = l & 31;

    // ---- P1: merge split-K partials ----
    {
        const int dg = tid >> 5;  // 0..7
        float m[KSPLIT], lv[KSPLIT];
        float M = -1e30f;
#pragma unroll
        for (int ks = 0; ks < KSPLIT; ks++) {
            m[ks] = ml[(size_t)(qblk * KSPLIT + ks) * 256 + wq * 32 + ql];
            lv[ks] = ml[(size_t)(qblk * KSPLIT + ks) * 256 + 128 + wq * 32 + ql];
            M = fmaxf(M, m[ks]);
        }
        float L = 0.f, f[KSPLIT];
#pragma unroll
        for (int ks = 0; ks < KSPLIT; ks++) { f[ks] = exp2f(m[ks] - M); L += lv[ks] * f[ks]; }
        float invL = 1.f / L;
        float acc[16];
#pragma unroll
        for (int i = 0; i < 16; i++) acc[i] = 0.f;
#pragma unroll
        for (int ks = 0; ks < KSPLIT; ks++) {
            size_t base = (((size_t)(qblk * KSPLIT + ks)) * 4 + wq) * (128 * 32);
#pragma unroll
            for (int i = 0; i < 16; i++)
                acc[i] += bf2f(Op[base + (size_t)(dg * 16 + i) * 32 + ql]) * f[ks];
        }
#pragma unroll
        for (int i = 0; i < 16; i++) Ct[ql][dg * 16 + i] = acc[i] * invL;
    }
    __syncthreads();
    // ---- P1b: residual with pre-layer H ----
    {
        const int d = tid & 127, rr = tid >> 7;
#pragma unroll
        for (int i = 0; i < 16; i++) {
            int row = rr * 16 + i;
            Ct[row][d] += H[(size_t)(m0 + row) * D + d];
        }
    }
    __syncthreads();
    // ---- P2: LN2 -> As ----
    ln_stats32(Ct, mu_s, rs_s, tid);
    __syncthreads();
    build_as(Ct, mu_s, rs_s, g2, b2l, As, tid);
    // ---- P3: MLP1 (gelu) -> midS ----
#pragma unroll
    for (int nc = 0; nc < 4; nc++) {
        __syncthreads();
        stage_w(W1l + (size_t)nc * 128 * D, D, Wst, tid);
        __syncthreads();
        f32x16 a = mm_32x128(As, Wst, wv, ql, h);
        const int n = nc * 128 + wv * 32 + ql;
        const int ch2 = n >> 3, sub = n & 7;
        const float bv = b1l[n];
#pragma unroll
        for (int r = 0; r < 16; r++) {
            int row = (r & 3) + 8 * (r >> 2) + 4 * h;
            float v = a[r] + bv;
            v = 0.5f * v * (1.f + erff(v * 0.7071067811865475f));
            midS[((size_t)ch2 * 32 + (row ^ (ch2 & 7))) * 8 + sub] = f2bf(v);
        }
    }
    // ---- P4: MLP2 ----
    f32x16 a2;
#pragma unroll
    for (int r = 0; r < 16; r++) a2[r] = 0.f;
#pragma unroll
    for (int kc = 0; kc < 4; kc++) {
        __syncthreads();
        stage_w(W2l + (size_t)kc * 128, HMID, Wst, tid);
        __syncthreads();
#pragma unroll
        for (int s = 0; s < 8; s++) {
            int ch = 2 * s + h;
            int gch = kc * 16 + ch;
            bf16x8 af = *(const bf16x8*)&midS[((size_t)gch * 32 + (ql ^ (gch & 7))) * 8];
            bf16x8 bf = *(const bf16x8*)&Wst[((size_t)ch * 128 + ((wv * 32 + ql) ^ ch)) * 8];
            a2 = __builtin_amdgcn_mfma_f32_32x32x16_bf16(af, bf, a2, 0, 0, 0);
        }
    }
    // ---- P5: bias + residual -> Ct, write H ----
    {
        const int col = wv * 32 + ql;
        const float bv = b2bias[col];
#pragma unroll
        for (int r = 0; r < 16; r++) {
            int row = (r & 3) + 8 * (r >> 2) + 4 * h;
            float v = a2[r] + bv + Ct[row][col];
            Ct[row][col] = v;
            H[(size_t)(m0 + row) * D + col] = v;
        }
    }
    __syncthreads();
    if (LAST) {
        const int q = tid >> 3, e8 = tid & 7;
        float s = 0.f;
#pragma unroll
        for (int c = 0; c < 16; c++) s += Ct[q][e8 * 16 + c] * Wro[e8 * 16 + c];
        s += __shfl_xor(s, 1); s += __shfl_xor(s, 2); s += __shfl_xor(s, 4);
        if (e8 == 0) outp[m0 + q] = s + bro[0];
    } else {
        // ---- P6: LN1(next) -> As, QKV(next) ----
        ln_stats32(Ct, mu_s, rs_s, tid);
        __syncthreads();
        build_as(Ct, mu_s, rs_s, g1n, b1n, As, tid);
        qkv_phase(As, Wqkvn, Wst, qb, kb, vt, m0, tid);
    }
}

extern "C" void kernel_launch(void* const* d_in, const int* in_sizes, int n_in,
                              void* d_out, int out_size, void* d_ws, size_t ws_size,
                              hipStream_t stream) {
    const int* x = (const int*)d_in[0];
    const float* pos = (const float*)d_in[1];
    const float* Wq = (const float*)d_in[2];
    const float* Wk = (const float*)d_in[3];
    const float* Wv = (const float*)d_in[4];
    const float* ln1g = (const float*)d_in[5];
    const float* ln1b = (const float*)d_in[6];
    const float* W1 = (const float*)d_in[7];
    const float* b1 = (const float*)d_in[8];
    const float* W2 = (const float*)d_in[9];
    const float* b2 = (const float*)d_in[10];
    const float* ln2g = (const float*)d_in[11];
    const float* ln2b = (const float*)d_in[12];
    const float* Wro = (const float*)d_in[13];
    const float* bro = (const float*)d_in[14];
    float* out = (float*)d_out;

    const size_t NTOK = (size_t)BATCH * T;  // 8192
    const size_t HSZ = NTOK * D;            // 1,048,576
    float* ws = (float*)d_ws;
    float* H = ws;                                   // f32 [8192][128]
    u16* qb = (u16*)(ws + HSZ);                      // bf16 [8192][128]
    u16* kb = (u16*)(ws + HSZ + HSZ / 2);
    u16* vt = (u16*)(ws + 2 * HSZ);                  // bf16 [B][128][2048]
    u16* Op = (u16*)(ws + 2 * HSZ + HSZ / 2);        // bf16 partials 16.8 MB
    float* mlbuf = ws + 7 * HSZ;                     // f32 131072
    u16* Wqkv = (u16*)(ws + 7 * HSZ + 131072);       // bf16 [L][3*128][128]
    u16* W1b = Wqkv + (size_t)NLAYER * 3 * D * D;
    u16* W2b = W1b + (size_t)NLAYER * HMID * D;

    const float qscale = 1.4426950408889634f / 11.313708498984761f;  // log2(e)/sqrt(D)

    conv_all<<<dim3(8448), 256, 0, stream>>>(Wq, Wk, Wv, W1, W2, Wqkv, W1b, W2b, qscale);
    embed_qkv<<<dim3(256), 256, 0, stream>>>(x, pos, ln1g, ln1b, Wqkv, qb, kb, vt, H);

    for (int lay = 0; lay < NLAYER; lay++) {
        attn_mfma<<<dim3(64, KSPLIT), 256, 0, stream>>>(qb, kb, vt, Op, mlbuf);
        if (lay < NLAYER - 1) {
            layer_tail<0><<<dim3(256), 256, 0, stream>>>(
                Op, mlbuf, H,
                ln2g + (size_t)lay * D, ln2b + (size_t)lay * D,
                W1b + (size_t)lay * HMID * D, b1 + (size_t)lay * HMID,
                W2b + (size_t)lay * D * HMID, b2 + (size_t)lay * D,
                ln1g + (size_t)(lay + 1) * D, ln1b + (size_t)(lay + 1) * D,
                Wqkv + (size_t)(lay + 1) * 3 * D * D,
                qb, kb, vt, Wro, bro, nullptr);
        } else {
            layer_tail<1><<<dim3(256), 256, 0, stream>>>(
                Op, mlbuf, H,
                ln2g + (size_t)lay * D, ln2b + (size_t)lay * D,
                W1b + (size_t)lay * HMID * D, b1 + (size_t)lay * HMID,
                W2b + (size_t)lay * D * HMID, b2 + (size_t)lay * D,
                ln1g, ln1b, Wqkv,
                qb, kb, vt, Wro, bro, out);
        }
    }
}